// Round 1
// 20886.958 us; speedup vs baseline: 1.1170x; 1.1170x over previous
//
#include <hip/hip_runtime.h>

// Persistent 8-team attention-GRU scan, register-resident x.
// Change vs 23.3ms baseline: produced data (Sf/AP/GB/GH/HB) is stored with
// WRITE-THROUGH sc0sc1 stores (visible at MALL on completion), so flag_arrive
// no longer needs the agent-release fence (buffer_wbl2 L2 sweep). Producer is
// now: vmcnt(0) drain + barrier + atomicMax token. Consumer unchanged:
// relaxed-agent flag poll + sc0sc1 loads of hot buffers. Weights/XT stay
// normal-cached (covered by the one-time init release/acquire).

typedef unsigned short u16;
typedef unsigned int u32;
typedef _Float16 h2 __attribute__((ext_vector_type(2)));
typedef _Float16 f16x8 __attribute__((ext_vector_type(8)));
typedef float f32x4 __attribute__((ext_vector_type(4)));
typedef float f32x2 __attribute__((ext_vector_type(2)));
typedef u32 u32x4 __attribute__((ext_vector_type(4)));

#define MAGIC 0x13579BDFu

// ---- workspace layout (bytes) ----
#define OFF_AW   65536      // attn_W f16 [512][1024]
#define OFF_CW   1114112    // comb_W f16 [512][1024]
#define OFF_WIH  2162688    // w_ih  f16 [1536][512]
#define OFF_WHH  3735552    // w_hh  f16 [1536][512]
#define OFF_OW   5308416    // out_W f16 [512][512]
#define OFF_HB   5832704    // h f16 [128][512]
#define OFF_SF   5963776    // scores f32 [128][512]
#define OFF_AP0  6225920    // applied half0 partial f32 [128][512]
#define OFF_AP1  6488064    // applied half1 partial f32 [128][512]
#define OFF_GB   6750208    // g f16 [128][512]
#define OFF_GH   6881280    // gh f32 [128][1536] (flat)
#define OFF_XT   7667712    // x^T f16 [128 b][512 t][512 m]  64 MiB
#define WS_NEED  74776576

// flag slot bases (u32 index into per-team ctrl[1024])
#define FS_S   64
#define FS_C   96
#define FS_G   128
#define FS_GH  160
#define FS_H   192
#define FS_RDY 224

__device__ __forceinline__ float sigmoidf_(float v) { return 1.f / (1.f + __expf(-v)); }
__device__ __forceinline__ float tanhf_(float v) {
  v = fminf(fmaxf(v, -15.f), 15.f);
  float e2 = __expf(2.f * v);
  return (e2 - 1.f) / (e2 + 1.f);
}
__device__ __forceinline__ u32 packh2(float a, float b) {
  h2 v; v.x = (_Float16)a; v.y = (_Float16)b;
  return __builtin_bit_cast(u32, v);
}

__device__ __forceinline__ void vm_drain() { asm volatile("s_waitcnt vmcnt(0)" ::: "memory"); }

// ---- coherent (sc0 sc1) LOAD helpers ----
__device__ __forceinline__ f32x2 ldg_f32x2(const void* p) {
  f32x2 r;
  asm volatile("global_load_dwordx2 %0, %1, off sc0 sc1\n\ts_waitcnt vmcnt(0)"
               : "=v"(r) : "v"(p) : "memory");
  return r;
}
__device__ __forceinline__ void ldg4x16(const void* p0, const void* p1, const void* p2,
                                        const void* p3, u32x4& a, u32x4& b, u32x4& c, u32x4& d) {
  asm volatile(
      "global_load_dwordx4 %0, %4, off sc0 sc1\n\t"
      "global_load_dwordx4 %1, %5, off sc0 sc1\n\t"
      "global_load_dwordx4 %2, %6, off sc0 sc1\n\t"
      "global_load_dwordx4 %3, %7, off sc0 sc1\n\t"
      "s_waitcnt vmcnt(0)"
      : "=&v"(a), "=&v"(b), "=&v"(c), "=&v"(d)
      : "v"(p0), "v"(p1), "v"(p2), "v"(p3) : "memory");
}
__device__ __forceinline__ void ldg3_f32(const float* p0, const float* p1, const float* p2,
                                         float& a, float& b, float& c) {
  asm volatile(
      "global_load_dword %0, %3, off sc0 sc1\n\t"
      "global_load_dword %1, %4, off sc0 sc1\n\t"
      "global_load_dword %2, %5, off sc0 sc1\n\t"
      "s_waitcnt vmcnt(0)"
      : "=&v"(a), "=&v"(b), "=&v"(c)
      : "v"(p0), "v"(p1), "v"(p2) : "memory");
}

// ---- coherent (sc0 sc1) WRITE-THROUGH store helpers ----
__device__ __forceinline__ void stg_f32(float* p, float v) {
  asm volatile("global_store_dword %0, %1, off sc0 sc1" :: "v"(p), "v"(v) : "memory");
}
__device__ __forceinline__ void stg_f32x2(float* p, f32x2 v) {
  asm volatile("global_store_dwordx2 %0, %1, off sc0 sc1" :: "v"(p), "v"(v) : "memory");
}
__device__ __forceinline__ void stg_u16(u16* p, u32 v) {
  asm volatile("global_store_short %0, %1, off sc0 sc1" :: "v"(p), "v"(v) : "memory");
}

// producer: all waves drain their write-through stores (vmcnt ack = at MALL),
// barrier orders all drains before tid0's flag. NO fence, NO buffer_wbl2.
__device__ __forceinline__ void flag_arrive(u32* ctrl, int fs, int slot, u32 tok) {
  vm_drain();
  __syncthreads();
  if (threadIdx.x == 0) {
    atomicMax(ctrl + fs + slot, tok);
  }
}
// consumer: all-wave relaxed-agent poll. NO acquire fence (all reads of
// produced data are sc0sc1 loads serviced at MALL).
__device__ __forceinline__ void flag_wait(u32* ctrl, int fs, int n, u32 tok, int lane) {
  if (tok == 0u) return;
  u32* p = ctrl + fs;
  for (;;) {
    u32 v = tok;
    if (lane < n) v = __hip_atomic_load(p + lane, __ATOMIC_RELAXED, __HIP_MEMORY_SCOPE_AGENT);
    if (__all((int)(v >= tok))) break;
  }
}

// stage 16 rows x 512 f16 (coherent loads) -> LDS rows, stride 520 f16 (1040 B)
__device__ __forceinline__ void stage_rows(const u16* gsrc, char* lds, int tid) {
  const int row = tid >> 4, c = tid & 15;
  const u16* g = gsrc + row * 512 + c * 32;
  u32x4 a, b, cc, d;
  ldg4x16(g, g + 8, g + 16, g + 24, a, b, cc, d);
  u32x4* dst = (u32x4*)(lds + row * 1040 + c * 64);
  dst[0] = a; dst[1] = b; dst[2] = cc; dst[3] = d;
}

#define MFMA(a, b, c) __builtin_amdgcn_mfma_f32_16x16x32_f16((a), (b), (c), 0, 0, 0)

extern "C" __global__ void __launch_bounds__(256, 1)
rnn_fused(const float* __restrict__ x, const float* __restrict__ attn_W,
          const float* __restrict__ attn_b, const float* __restrict__ comb_W,
          const float* __restrict__ comb_b, const float* __restrict__ w_ih,
          const float* __restrict__ w_hh, const float* __restrict__ b_ih,
          const float* __restrict__ b_hh, const float* __restrict__ out_W,
          const float* __restrict__ out_b, float* __restrict__ out,
          char* __restrict__ ws)
{
  const int tid  = threadIdx.x;
  const int lane = tid & 63;
  const int warp = tid >> 6;
  const int team = blockIdx.x & 7;
  const int tb   = blockIdx.x >> 3;     // 0..31 within team
  const int tt   = tb * 256 + tid;      // team thread id
  const int gb0  = team * 16;
  const int lb   = tb >> 1;             // pair index -> batch
  const int half = tb & 1;              // m-half of x held by this block
  const int b    = gb0 + lb;            // this block's batch (x holder / stage C)
  const int m0h  = half * 256;

  u32* ctrl = (u32*)ws + team * 1024;   // 4 KB per team

  u16*   AW  = (u16*)(ws + OFF_AW);
  u16*   CW  = (u16*)(ws + OFF_CW);
  u16*   WIH = (u16*)(ws + OFF_WIH);
  u16*   WHH = (u16*)(ws + OFF_WHH);
  u16*   OW  = (u16*)(ws + OFF_OW);
  u16*   HB  = (u16*)(ws + OFF_HB);
  float* Sf  = (float*)(ws + OFF_SF);
  float* AP0 = (float*)(ws + OFF_AP0);
  float* AP1 = (float*)(ws + OFF_AP1);
  u16*   GB  = (u16*)(ws + OFF_GB);
  float* GH  = (float*)(ws + OFF_GH);
  u16*   XT  = (u16*)(ws + OFF_XT);

  __shared__ char smem[16704];
  float*     tbuf   = (float*)smem;           // [64][65] f32, init transpose only
  u32*       pLDS   = (u32*)smem;             // [128] packed f16 p-pairs (stage C)
  float*     redbuf = (float*)(smem + 512);   // [4][512] stage C partials
  float*     rbuf   = (float*)(smem + 8704);  // [8] softmax reduce scratch
  _Float16*  ldsF   = (_Float16*)smem;        // staged fragments, row stride 520

  // ---- init handshake (per team): block 0 zeroes ctrl, sets magic ----
  if (tb == 0) {
    for (int i = 1 + tid; i < 1024; i += 256) ctrl[i] = 0u;
    __syncthreads();
    if (tid == 0) { __threadfence(); atomicExch(ctrl, MAGIC); }
  }
  if (tid == 0) {
    while (__hip_atomic_load(ctrl, __ATOMIC_RELAXED, __HIP_MEMORY_SCOPE_AGENT) != MAGIC) {}
    __threadfence();
  }
  __syncthreads();

  // ---- phase 0a: weights -> f16 (team-redundant, same-value benign races) ----
  for (int i = tt; i < 512 * 1024; i += 8192) AW[i]  = __builtin_bit_cast(u16, (_Float16)attn_W[i]);
  for (int i = tt; i < 512 * 1024; i += 8192) CW[i]  = __builtin_bit_cast(u16, (_Float16)comb_W[i]);
  for (int i = tt; i < 1536 * 512; i += 8192) WIH[i] = __builtin_bit_cast(u16, (_Float16)w_ih[i]);
  for (int i = tt; i < 1536 * 512; i += 8192) WHH[i] = __builtin_bit_cast(u16, (_Float16)w_hh[i]);
  for (int i = tt; i < 512 * 512;  i += 8192) OW[i]  = __builtin_bit_cast(u16, (_Float16)out_W[i]);
  HB[(size_t)gb0 * 512 + tt] = 0;   // h0 = 0

  // ---- phase 0b: transpose this block's m-half of x[b] into XT[b][t][m] (f16) ----
  {
    const float* xb  = x  + (size_t)b * 512 * 512;
    u16*         xtB = XT + (size_t)b * 512 * 512;
    for (int mt = 0; mt < 4; ++mt) {
      for (int ct = 0; ct < 8; ++ct) {
        for (int rr = warp; rr < 64; rr += 4)
          tbuf[rr * 65 + lane] = xb[(size_t)(m0h + mt * 64 + rr) * 512 + ct * 64 + lane];
        __syncthreads();
        for (int rr = warp; rr < 64; rr += 4)
          xtB[(size_t)(ct * 64 + rr) * 512 + m0h + mt * 64 + lane] =
              __builtin_bit_cast(u16, (_Float16)tbuf[lane * 65 + rr]);
        __syncthreads();
      }
    }
  }

  // init release (full fence: pushes weights/XT/HB to MALL), RDY, one-time acquire
  vm_drain();
  __syncthreads();
  if (tid == 0) { __threadfence(); atomicMax(ctrl + FS_RDY + tb, 1u); }
  {
    u32* p = ctrl + FS_RDY;
    for (;;) {
      u32 v = 1u;
      if (lane < 32) v = __hip_atomic_load(p + lane, __ATOMIC_RELAXED, __HIP_MEMORY_SCOPE_AGENT);
      if (__all((int)(v >= 1u))) break;
    }
  }
  __syncthreads();
  __threadfence();   // one-time acquire: L1/L2 inv so normal XT/weight loads are fresh

  // ---- phase 0c: register-resident x: rows t=lane*8+r, cols m0h+warp*64.. ----
  uint4 xr4[64];
  {
    const u16* base = XT + (size_t)b * 262144 + m0h + warp * 64;
#pragma unroll
    for (int r = 0; r < 8; ++r) {
      const uint4* row = (const uint4*)(base + (size_t)(lane * 8 + r) * 512);
#pragma unroll
      for (int jj = 0; jj < 8; ++jj) xr4[r * 8 + jj] = row[jj];
    }
  }

  const int  r16 = lane & 15, q = lane >> 4, q8 = q * 8;
  const bool isA = (tb < 8), isW = (tb >= 8 && tb < 16);
  const int  W4 = ((tb < 8) ? tb : tb - 8) * 4 + warp;
  const int  n0 = W4 * 16;

  float biasA = 0.f, biasD = 0.f, biasI0 = 0.f, biasI1 = 0.f, biasI2 = 0.f,
        biasH0 = 0.f, biasH1 = 0.f, biasH2 = 0.f, biasO = 0.f;
  if (isA) {
    biasA = attn_b[n0 + r16]; biasD = comb_b[n0 + r16];
    biasI0 = b_ih[n0 + r16]; biasI1 = b_ih[512 + n0 + r16]; biasI2 = b_ih[1024 + n0 + r16];
    biasO = out_b[n0 + r16];
  }
  if (isW) {
    biasH0 = b_hh[n0 + r16]; biasH1 = b_hh[512 + n0 + r16]; biasH2 = b_hh[1024 + n0 + r16];
  }

  float hreg[4] = {0.f, 0.f, 0.f, 0.f};

  for (int t = 0; t < 512; ++t) {
    const u32 tok = (u32)(t + 1);

    if (isA) {
      flag_wait(ctrl, FS_H, 8, (u32)t, lane);
      __syncthreads();                         // all waves past wait before LDS reuse
      stage_rows(HB + gb0 * 512, smem, tid);   // coherent h -> LDS
      __syncthreads();
      // stage A: S = [x(:,t) | h] @ attn_W^T + attn_b
      f32x4 acc = {0.f, 0.f, 0.f, 0.f};
      const u16* aXp = XT + (size_t)(gb0 + r16) * 262144 + (size_t)t * 512 + q8;
      const _Float16* aHl = ldsF + r16 * 520 + q8;
      const u16* bWp = AW + (size_t)(n0 + r16) * 1024 + q8;
#pragma unroll 4
      for (int k0 = 0; k0 < 512; k0 += 32)
        acc = MFMA(*(const f16x8*)(aXp + k0), *(const f16x8*)(bWp + k0), acc);
#pragma unroll 4
      for (int k0 = 0; k0 < 512; k0 += 32)
        acc = MFMA(*(const f16x8*)(aHl + k0), *(const f16x8*)(bWp + 512 + k0), acc);
#pragma unroll
      for (int i = 0; i < 4; ++i)
        stg_f32(Sf + (size_t)(gb0 + q * 4 + i) * 512 + n0 + r16, acc[i] + biasA);  // write-through
      flag_arrive(ctrl, FS_S, tb, tok);
    } else if (isW) {
      flag_wait(ctrl, FS_H, 8, (u32)t, lane);
      __syncthreads();
      stage_rows(HB + gb0 * 512, smem, tid);
      __syncthreads();
      // gh = h @ w_hh^T + b_hh (3 gate tiles, shared A-fragment)
      f32x4 a0 = {0.f,0.f,0.f,0.f}, a1 = {0.f,0.f,0.f,0.f}, a2 = {0.f,0.f,0.f,0.f};
      const _Float16* aHl = ldsF + r16 * 520 + q8;
      const u16* b0p = WHH + (size_t)(n0 + r16) * 512 + q8;
      const u16* b1p = WHH + (size_t)(512 + n0 + r16) * 512 + q8;
      const u16* b2p = WHH + (size_t)(1024 + n0 + r16) * 512 + q8;
#pragma unroll 4
      for (int k0 = 0; k0 < 512; k0 += 32) {
        f16x8 a = *(const f16x8*)(aHl + k0);
        a0 = MFMA(a, *(const f16x8*)(b0p + k0), a0);
        a1 = MFMA(a, *(const f16x8*)(b1p + k0), a1);
        a2 = MFMA(a, *(const f16x8*)(b2p + k0), a2);
      }
#pragma unroll
      for (int i = 0; i < 4; ++i) {            // write-through stores, flat layout
        const size_t ro = (size_t)(gb0 + q * 4 + i) * 1536;
        stg_f32(GH + ro + n0 + r16,        a0[i] + biasH0);
        stg_f32(GH + ro + 512 + n0 + r16,  a1[i] + biasH1);
        stg_f32(GH + ro + 1024 + n0 + r16, a2[i] + biasH2);
      }
      flag_arrive(ctrl, FS_GH, tb - 8, tok);
    }

    // ---- all blocks: softmax (own batch) + applied partials from register x ----
    flag_wait(ctrl, FS_S, 8, tok, lane);
    {
      const int tc = 2 * tid;
      f32x2 sv = ldg_f32x2(Sf + (size_t)b * 512 + tc);   // coherent read
      float s0 = sv.x, s1 = sv.y;
      float mx = fmaxf(s0, s1);
#pragma unroll
      for (int off = 32; off; off >>= 1) mx = fmaxf(mx, __shfl_xor(mx, off, 64));
      if (lane == 0) rbuf[warp] = mx;
      __syncthreads();
      mx = fmaxf(fmaxf(rbuf[0], rbuf[1]), fmaxf(rbuf[2], rbuf[3]));
      float e0 = __expf(s0 - mx), e1 = __expf(s1 - mx);
      float sm = e0 + e1;
#pragma unroll
      for (int off = 32; off; off >>= 1) sm += __shfl_xor(sm, off, 64);
      if (lane == 0) rbuf[4 + warp] = sm;
      __syncthreads();
      sm = rbuf[4] + rbuf[5] + rbuf[6] + rbuf[7];
      const float inv = 1.f / sm;
      if ((tid >> 7) == half) {
        pLDS[tid & 127] = packh2(e0 * inv, e1 * inv);
      }
      __syncthreads();

      uint4 pz4[8];
      const uint4* pp = (const uint4*)pLDS + warp * 8;
#pragma unroll
      for (int jj = 0; jj < 8; ++jj) pz4[jj] = pp[jj];
      float accr[8];
#pragma unroll
      for (int r = 0; r < 8; ++r) {
        h2 sA = {(_Float16)0.f, (_Float16)0.f};
        h2 sB = {(_Float16)0.f, (_Float16)0.f};
#pragma unroll
        for (int jj = 0; jj < 8; ++jj) {
          uint4 xw = xr4[r * 8 + jj], pw = pz4[jj];
          sA = __builtin_bit_cast(h2, xw.x) * __builtin_bit_cast(h2, pw.x) + sA;
          sB = __builtin_bit_cast(h2, xw.y) * __builtin_bit_cast(h2, pw.y) + sB;
          sA = __builtin_bit_cast(h2, xw.z) * __builtin_bit_cast(h2, pw.z) + sA;
          sB = __builtin_bit_cast(h2, xw.w) * __builtin_bit_cast(h2, pw.w) + sB;
        }
        accr[r] = (float)sA.x + (float)sA.y + (float)sB.x + (float)sB.y;
      }
#pragma unroll
      for (int r = 0; r < 8; ++r) redbuf[warp * 512 + lane * 8 + r] = accr[r];
      __syncthreads();
      {
        float v0 = redbuf[tc]     + redbuf[512 + tc]     + redbuf[1024 + tc]     + redbuf[1536 + tc];
        float v1 = redbuf[tc + 1] + redbuf[512 + tc + 1] + redbuf[1024 + tc + 1] + redbuf[1536 + tc + 1];
        float* dst = (half ? AP1 : AP0) + (size_t)b * 512 + tc;
        f32x2 vv; vv.x = v0; vv.y = v1;
        stg_f32x2(dst, vv);                               // write-through
      }
      flag_arrive(ctrl, FS_C, tb, tok);
    }

    if (isA) {
      // stage D: g = relu([x(:,t) | applied] @ comb_W^T + comb_b); x-part first
      f32x4 acc = {0.f, 0.f, 0.f, 0.f};
      const u16* aXp = XT + (size_t)(gb0 + r16) * 262144 + (size_t)t * 512 + q8;
      const u16* bWp = CW + (size_t)(n0 + r16) * 1024 + q8;
#pragma unroll 4
      for (int k0 = 0; k0 < 512; k0 += 32)
        acc = MFMA(*(const f16x8*)(aXp + k0), *(const f16x8*)(bWp + k0), acc);
      flag_wait(ctrl, FS_C, 32, tok, lane);
      __syncthreads();
      {  // stage applied = AP0+AP1 (coherent f32 reads) -> f16 LDS rows
        const int row = tid >> 4, c = tid & 15;
        const float* g0 = AP0 + (size_t)(gb0 + row) * 512 + c * 32;
        const float* g1 = AP1 + (size_t)(gb0 + row) * 512 + c * 32;
        u32* dst = (u32*)(smem + row * 1040 + c * 64);
        u32x4 A0, A1, A2, A3, B0, B1, B2, B3, C0, C1, C2, C3, D0, D1, D2, D3;
        ldg4x16(g0,      g0 + 4,  g0 + 8,  g0 + 12, A0, A1, A2, A3);
        ldg4x16(g0 + 16, g0 + 20, g0 + 24, g0 + 28, B0, B1, B2, B3);
        ldg4x16(g1,      g1 + 4,  g1 + 8,  g1 + 12, C0, C1, C2, C3);
        ldg4x16(g1 + 16, g1 + 20, g1 + 24, g1 + 28, D0, D1, D2, D3);
        f32x4 s0 = __builtin_bit_cast(f32x4, A0) + __builtin_bit_cast(f32x4, C0);
        f32x4 s1 = __builtin_bit_cast(f32x4, A1) + __builtin_bit_cast(f32x4, C1);
        f32x4 s2 = __builtin_bit_cast(f32x4, A2) + __builtin_bit_cast(f32x4, C2);
        f32x4 s3 = __builtin_bit_cast(f32x4, A3) + __builtin_bit_cast(f32x4, C3);
        f32x4 s4 = __builtin_bit_cast(f32x4, B0) + __builtin_bit_cast(f32x4, D0);
        f32x4 s5 = __builtin_bit_cast(f32x4, B1) + __builtin_bit_cast(f32x4, D1);
        f32x4 s6 = __builtin_bit_cast(f32x4, B2) + __builtin_bit_cast(f32x4, D2);
        f32x4 s7 = __builtin_bit_cast(f32x4, B3) + __builtin_bit_cast(f32x4, D3);
        dst[0]  = packh2(s0[0], s0[1]); dst[1]  = packh2(s0[2], s0[3]);
        dst[2]  = packh2(s1[0], s1[1]); dst[3]  = packh2(s1[2], s1[3]);
        dst[4]  = packh2(s2[0], s2[1]); dst[5]  = packh2(s2[2], s2[3]);
        dst[6]  = packh2(s3[0], s3[1]); dst[7]  = packh2(s3[2], s3[3]);
        dst[8]  = packh2(s4[0], s4[1]); dst[9]  = packh2(s4[2], s4[3]);
        dst[10] = packh2(s5[0], s5[1]); dst[11] = packh2(s5[2], s5[3]);
        dst[12] = packh2(s6[0], s6[1]); dst[13] = packh2(s6[2], s6[3]);
        dst[14] = packh2(s7[0], s7[1]); dst[15] = packh2(s7[2], s7[3]);
      }
      __syncthreads();
      const _Float16* aAl = ldsF + r16 * 520 + q8;
#pragma unroll 4
      for (int k0 = 0; k0 < 512; k0 += 32)
        acc = MFMA(*(const f16x8*)(aAl + k0), *(const f16x8*)(bWp + 512 + k0), acc);
#pragma unroll
      for (int i = 0; i < 4; ++i) {
        float g = fmaxf(acc[i] + biasD, 0.f);
        stg_u16(GB + (size_t)(gb0 + q * 4 + i) * 512 + n0 + r16,
                (u32)__builtin_bit_cast(u16, (_Float16)g));   // write-through
      }
      flag_arrive(ctrl, FS_G, tb, tok);
      flag_wait(ctrl, FS_G, 8, tok, lane);
      __syncthreads();
      stage_rows(GB + gb0 * 512, smem, tid);   // coherent g -> LDS
      __syncthreads();

      // stage EF: gi = g @ w_ih^T + b_ih (3 gates), then fused GRU pointwise
      f32x4 g0 = {0.f,0.f,0.f,0.f}, g1 = {0.f,0.f,0.f,0.f}, g2 = {0.f,0.f,0.f,0.f};
      const _Float16* aGl = ldsF + r16 * 520 + q8;
      const u16* w0p = WIH + (size_t)(n0 + r16) * 512 + q8;
      const u16* w1p = WIH + (size_t)(512 + n0 + r16) * 512 + q8;
      const u16* w2p = WIH + (size_t)(1024 + n0 + r16) * 512 + q8;
#pragma unroll 4
      for (int k0 = 0; k0 < 512; k0 += 32) {
        f16x8 a = *(const f16x8*)(aGl + k0);
        g0 = MFMA(a, *(const f16x8*)(w0p + k0), g0);
        g1 = MFMA(a, *(const f16x8*)(w1p + k0), g1);
        g2 = MFMA(a, *(const f16x8*)(w2p + k0), g2);
      }
      flag_wait(ctrl, FS_GH, 8, tok, lane);
#pragma unroll
      for (int i = 0; i < 4; ++i) {
        const int bi = gb0 + q * 4 + i;
        const size_t ro = (size_t)bi * 1536;
        const int j = n0 + r16;
        float ghr_, ghz_, ghn_;
        ldg3_f32(GH + ro + j, GH + ro + 512 + j, GH + ro + 1024 + j, ghr_, ghz_, ghn_);
        float gir = g0[i] + biasI0, giz = g1[i] + biasI1, gin = g2[i] + biasI2;
        float rg = sigmoidf_(gir + ghr_);
        float zg = sigmoidf_(giz + ghz_);
        float ng = tanhf_(gin + rg * ghn_);
        hreg[i] = (1.f - zg) * ng + zg * hreg[i];
        stg_u16(HB + (size_t)bi * 512 + j,
                (u32)__builtin_bit_cast(u16, (_Float16)hreg[i]));  // write-through
      }
      flag_arrive(ctrl, FS_H, tb, tok);
    }
  }

  // ---- epilogue: out = h @ out_W^T + out_b ----
  if (isA) {
    flag_wait(ctrl, FS_H, 8, 512u, lane);
    __syncthreads();
    stage_rows(HB + gb0 * 512, smem, tid);
    __syncthreads();
    f32x4 acc = {0.f, 0.f, 0.f, 0.f};
    const _Float16* aHl = ldsF + r16 * 520 + q8;
    const u16* bOp = OW + (size_t)(n0 + r16) * 512 + q8;
#pragma unroll 4
    for (int k0 = 0; k0 < 512; k0 += 32)
      acc = MFMA(*(const f16x8*)(aHl + k0), *(const f16x8*)(bOp + k0), acc);
#pragma unroll
    for (int i = 0; i < 4; ++i)
      out[(size_t)(gb0 + q * 4 + i) * 512 + n0 + r16] = acc[i] + biasO;
  }
}

extern "C" void kernel_launch(void* const* d_in, const int* in_sizes, int n_in,
                              void* d_out, int out_size, void* d_ws, size_t ws_size,
                              hipStream_t stream) {
  if (ws_size < (size_t)WS_NEED) return;
  rnn_fused<<<dim3(256), dim3(256), 0, stream>>>(
      (const float*)d_in[0], (const float*)d_in[1], (const float*)d_in[2],
      (const float*)d_in[3], (const float*)d_in[4], (const float*)d_in[5],
      (const float*)d_in[6], (const float*)d_in[7], (const float*)d_in[8],
      (const float*)d_in[9], (const float*)d_in[10],
      (float*)d_out, (char*)d_ws);
}

// Round 2
// 20122.626 us; speedup vs baseline: 1.1594x; 1.0380x over previous
//
#include <hip/hip_runtime.h>

// Persistent 8-team attention-GRU scan, register-resident x.
// Round-2 changes (sync fabric only, data path identical):
//  * counter-based stage flags: one u32 per stage per team; producers
//    atomicAdd(+1), consumers wait counter >= N*token. Polls read ONE dword.
//  * single-wave polling: wave 0 spins, other waves wait at __syncthreads.
//  * batched coherent loads: AP staging = 16 loads / ONE vmcnt(0);
//    GH gate read = 12 loads / ONE vmcnt(0) (signed offset immediates).
// Producer visibility unchanged: write-through sc0sc1 stores + vmcnt drain
// + barrier + atomic counter bump (no fence, no L2 sweep).

typedef unsigned short u16;
typedef unsigned int u32;
typedef _Float16 h2 __attribute__((ext_vector_type(2)));
typedef _Float16 f16x8 __attribute__((ext_vector_type(8)));
typedef float f32x4 __attribute__((ext_vector_type(4)));
typedef float f32x2 __attribute__((ext_vector_type(2)));
typedef u32 u32x4 __attribute__((ext_vector_type(4)));

#define MAGIC 0x13579BDFu

// ---- workspace layout (bytes) ----
#define OFF_AW   65536      // attn_W f16 [512][1024]
#define OFF_CW   1114112    // comb_W f16 [512][1024]
#define OFF_WIH  2162688    // w_ih  f16 [1536][512]
#define OFF_WHH  3735552    // w_hh  f16 [1536][512]
#define OFF_OW   5308416    // out_W f16 [512][512]
#define OFF_HB   5832704    // h f16 [128][512]
#define OFF_SF   5963776    // scores f32 [128][512]
#define OFF_AP0  6225920    // applied half0 partial f32 [128][512]
#define OFF_AP1  6488064    // applied half1 partial f32 [128][512]
#define OFF_GB   6750208    // g f16 [128][512]
#define OFF_GH   6881280    // gh f32 [128][1536] (flat)
#define OFF_XT   7667712    // x^T f16 [128 b][512 t][512 m]  64 MiB
#define WS_NEED  74776576

// per-stage counter slots (u32 index into per-team ctrl[1024]); 128B apart
#define FS_S   64
#define FS_C   96
#define FS_G   128
#define FS_GH  160
#define FS_H   192
#define FS_RDY 224

__device__ __forceinline__ float sigmoidf_(float v) { return 1.f / (1.f + __expf(-v)); }
__device__ __forceinline__ float tanhf_(float v) {
  v = fminf(fmaxf(v, -15.f), 15.f);
  float e2 = __expf(2.f * v);
  return (e2 - 1.f) / (e2 + 1.f);
}
__device__ __forceinline__ u32 packh2(float a, float b) {
  h2 v; v.x = (_Float16)a; v.y = (_Float16)b;
  return __builtin_bit_cast(u32, v);
}

__device__ __forceinline__ void vm_drain() { asm volatile("s_waitcnt vmcnt(0)" ::: "memory"); }

// ---- coherent (sc0 sc1) LOAD helpers ----
__device__ __forceinline__ f32x2 ldg_f32x2(const void* p) {
  f32x2 r;
  asm volatile("global_load_dwordx2 %0, %1, off sc0 sc1\n\ts_waitcnt vmcnt(0)"
               : "=v"(r) : "v"(p) : "memory");
  return r;
}
// 4 x dwordx4 from one base via offset immediates, one wait
__device__ __forceinline__ void ldg4x16_off(const void* p, u32x4& a, u32x4& b, u32x4& c, u32x4& d) {
  asm volatile(
      "global_load_dwordx4 %0, %4, off sc0 sc1\n\t"
      "global_load_dwordx4 %1, %4, off offset:16 sc0 sc1\n\t"
      "global_load_dwordx4 %2, %4, off offset:32 sc0 sc1\n\t"
      "global_load_dwordx4 %3, %4, off offset:48 sc0 sc1\n\t"
      "s_waitcnt vmcnt(0)"
      : "=&v"(a), "=&v"(b), "=&v"(c), "=&v"(d)
      : "v"(p) : "memory");
}
// 16 x dwordx4 (two 128B-contiguous rows), ONE wait. Outputs valid after return.
__device__ __forceinline__ void ldg_ap16(const float* pa, const float* pb,
                                         u32x4 (&A)[8], u32x4 (&B)[8]) {
  asm volatile(
      "global_load_dwordx4 %0, %16, off sc0 sc1\n\t"
      "global_load_dwordx4 %1, %16, off offset:16 sc0 sc1\n\t"
      "global_load_dwordx4 %2, %16, off offset:32 sc0 sc1\n\t"
      "global_load_dwordx4 %3, %16, off offset:48 sc0 sc1\n\t"
      "global_load_dwordx4 %4, %16, off offset:64 sc0 sc1\n\t"
      "global_load_dwordx4 %5, %16, off offset:80 sc0 sc1\n\t"
      "global_load_dwordx4 %6, %16, off offset:96 sc0 sc1\n\t"
      "global_load_dwordx4 %7, %16, off offset:112 sc0 sc1\n\t"
      "global_load_dwordx4 %8, %17, off sc0 sc1\n\t"
      "global_load_dwordx4 %9, %17, off offset:16 sc0 sc1\n\t"
      "global_load_dwordx4 %10, %17, off offset:32 sc0 sc1\n\t"
      "global_load_dwordx4 %11, %17, off offset:48 sc0 sc1\n\t"
      "global_load_dwordx4 %12, %17, off offset:64 sc0 sc1\n\t"
      "global_load_dwordx4 %13, %17, off offset:80 sc0 sc1\n\t"
      "global_load_dwordx4 %14, %17, off offset:96 sc0 sc1\n\t"
      "global_load_dwordx4 %15, %17, off offset:112 sc0 sc1\n\t"
      "s_waitcnt vmcnt(0)"
      : "=&v"(A[0]), "=&v"(A[1]), "=&v"(A[2]), "=&v"(A[3]),
        "=&v"(A[4]), "=&v"(A[5]), "=&v"(A[6]), "=&v"(A[7]),
        "=&v"(B[0]), "=&v"(B[1]), "=&v"(B[2]), "=&v"(B[3]),
        "=&v"(B[4]), "=&v"(B[5]), "=&v"(B[6]), "=&v"(B[7])
      : "v"(pa), "v"(pb) : "memory");
}
// 12 GH gate values (r/z/n for 4 rows) via one base per row (+-2048B offsets), ONE wait
__device__ __forceinline__ void ldg_gh12(const float* q0, const float* q1,
                                         const float* q2, const float* q3,
                                         float (&rr)[4], float (&zz)[4], float (&nn)[4]) {
  asm volatile(
      "global_load_dword %0, %12, off offset:-2048 sc0 sc1\n\t"
      "global_load_dword %4, %12, off sc0 sc1\n\t"
      "global_load_dword %8, %12, off offset:2048 sc0 sc1\n\t"
      "global_load_dword %1, %13, off offset:-2048 sc0 sc1\n\t"
      "global_load_dword %5, %13, off sc0 sc1\n\t"
      "global_load_dword %9, %13, off offset:2048 sc0 sc1\n\t"
      "global_load_dword %2, %14, off offset:-2048 sc0 sc1\n\t"
      "global_load_dword %6, %14, off sc0 sc1\n\t"
      "global_load_dword %10, %14, off offset:2048 sc0 sc1\n\t"
      "global_load_dword %3, %15, off offset:-2048 sc0 sc1\n\t"
      "global_load_dword %7, %15, off sc0 sc1\n\t"
      "global_load_dword %11, %15, off offset:2048 sc0 sc1\n\t"
      "s_waitcnt vmcnt(0)"
      : "=&v"(rr[0]), "=&v"(rr[1]), "=&v"(rr[2]), "=&v"(rr[3]),
        "=&v"(zz[0]), "=&v"(zz[1]), "=&v"(zz[2]), "=&v"(zz[3]),
        "=&v"(nn[0]), "=&v"(nn[1]), "=&v"(nn[2]), "=&v"(nn[3])
      : "v"(q0), "v"(q1), "v"(q2), "v"(q3) : "memory");
}

// ---- coherent (sc0 sc1) WRITE-THROUGH store helpers ----
__device__ __forceinline__ void stg_f32(float* p, float v) {
  asm volatile("global_store_dword %0, %1, off sc0 sc1" :: "v"(p), "v"(v) : "memory");
}
__device__ __forceinline__ void stg_f32x2(float* p, f32x2 v) {
  asm volatile("global_store_dwordx2 %0, %1, off sc0 sc1" :: "v"(p), "v"(v) : "memory");
}
__device__ __forceinline__ void stg_u16(u16* p, u32 v) {
  asm volatile("global_store_short %0, %1, off sc0 sc1" :: "v"(p), "v"(v) : "memory");
}

// producer: drain write-through stores (vmcnt ack = at coherence point),
// barrier orders all waves' drains before tid0's counter bump.
__device__ __forceinline__ void flag_add(u32* ctrl, int fs) {
  vm_drain();
  __syncthreads();
  if (threadIdx.x == 0) atomicAdd(ctrl + fs, 1u);
}
// consumer: wave 0 polls ONE dword, everyone else parks at the barrier.
__device__ __forceinline__ void flag_wait_ge(u32* ctrl, int fs, u32 target, int warp) {
  if (warp == 0) {
    u32 v;
    do {
      v = __hip_atomic_load(ctrl + fs, __ATOMIC_RELAXED, __HIP_MEMORY_SCOPE_AGENT);
    } while (v < target);
  }
  __syncthreads();
}

// stage 16 rows x 512 f16 (coherent loads) -> LDS rows, stride 520 f16 (1040 B)
__device__ __forceinline__ void stage_rows(const u16* gsrc, char* lds, int tid) {
  const int row = tid >> 4, c = tid & 15;
  const u16* g = gsrc + row * 512 + c * 32;
  u32x4 a, b, cc, d;
  ldg4x16_off(g, a, b, cc, d);
  u32x4* dst = (u32x4*)(lds + row * 1040 + c * 64);
  dst[0] = a; dst[1] = b; dst[2] = cc; dst[3] = d;
}

#define MFMA(a, b, c) __builtin_amdgcn_mfma_f32_16x16x32_f16((a), (b), (c), 0, 0, 0)

extern "C" __global__ void __launch_bounds__(256, 1)
rnn_fused(const float* __restrict__ x, const float* __restrict__ attn_W,
          const float* __restrict__ attn_b, const float* __restrict__ comb_W,
          const float* __restrict__ comb_b, const float* __restrict__ w_ih,
          const float* __restrict__ w_hh, const float* __restrict__ b_ih,
          const float* __restrict__ b_hh, const float* __restrict__ out_W,
          const float* __restrict__ out_b, float* __restrict__ out,
          char* __restrict__ ws)
{
  const int tid  = threadIdx.x;
  const int lane = tid & 63;
  const int warp = tid >> 6;
  const int team = blockIdx.x & 7;
  const int tb   = blockIdx.x >> 3;     // 0..31 within team
  const int tt   = tb * 256 + tid;      // team thread id
  const int gb0  = team * 16;
  const int lb   = tb >> 1;             // pair index -> batch
  const int half = tb & 1;              // m-half of x held by this block
  const int b    = gb0 + lb;            // this block's batch (x holder / stage C)
  const int m0h  = half * 256;

  u32* ctrl = (u32*)ws + team * 1024;   // 4 KB per team

  u16*   AW  = (u16*)(ws + OFF_AW);
  u16*   CW  = (u16*)(ws + OFF_CW);
  u16*   WIH = (u16*)(ws + OFF_WIH);
  u16*   WHH = (u16*)(ws + OFF_WHH);
  u16*   OW  = (u16*)(ws + OFF_OW);
  u16*   HB  = (u16*)(ws + OFF_HB);
  float* Sf  = (float*)(ws + OFF_SF);
  float* AP0 = (float*)(ws + OFF_AP0);
  float* AP1 = (float*)(ws + OFF_AP1);
  u16*   GB  = (u16*)(ws + OFF_GB);
  float* GH  = (float*)(ws + OFF_GH);
  u16*   XT  = (u16*)(ws + OFF_XT);

  __shared__ char smem[16704];
  float*     tbuf   = (float*)smem;           // [64][65] f32, init transpose only
  u32*       pLDS   = (u32*)smem;             // [128] packed f16 p-pairs (stage C)
  float*     redbuf = (float*)(smem + 512);   // [4][512] stage C partials
  float*     rbuf   = (float*)(smem + 8704);  // [8] softmax reduce scratch
  _Float16*  ldsF   = (_Float16*)smem;        // staged fragments, row stride 520

  // ---- init handshake (per team): block 0 zeroes ctrl, sets magic ----
  if (tb == 0) {
    for (int i = 1 + tid; i < 1024; i += 256) ctrl[i] = 0u;
    __syncthreads();
    if (tid == 0) { __threadfence(); atomicExch(ctrl, MAGIC); }
  }
  if (tid == 0) {
    while (__hip_atomic_load(ctrl, __ATOMIC_RELAXED, __HIP_MEMORY_SCOPE_AGENT) != MAGIC) {}
    __threadfence();
  }
  __syncthreads();

  // ---- phase 0a: weights -> f16 (team-redundant, same-value benign races) ----
  for (int i = tt; i < 512 * 1024; i += 8192) AW[i]  = __builtin_bit_cast(u16, (_Float16)attn_W[i]);
  for (int i = tt; i < 512 * 1024; i += 8192) CW[i]  = __builtin_bit_cast(u16, (_Float16)comb_W[i]);
  for (int i = tt; i < 1536 * 512; i += 8192) WIH[i] = __builtin_bit_cast(u16, (_Float16)w_ih[i]);
  for (int i = tt; i < 1536 * 512; i += 8192) WHH[i] = __builtin_bit_cast(u16, (_Float16)w_hh[i]);
  for (int i = tt; i < 512 * 512;  i += 8192) OW[i]  = __builtin_bit_cast(u16, (_Float16)out_W[i]);
  HB[(size_t)gb0 * 512 + tt] = 0;   // h0 = 0

  // ---- phase 0b: transpose this block's m-half of x[b] into XT[b][t][m] (f16) ----
  {
    const float* xb  = x  + (size_t)b * 512 * 512;
    u16*         xtB = XT + (size_t)b * 512 * 512;
    for (int mt = 0; mt < 4; ++mt) {
      for (int ct = 0; ct < 8; ++ct) {
        for (int rr = warp; rr < 64; rr += 4)
          tbuf[rr * 65 + lane] = xb[(size_t)(m0h + mt * 64 + rr) * 512 + ct * 64 + lane];
        __syncthreads();
        for (int rr = warp; rr < 64; rr += 4)
          xtB[(size_t)(ct * 64 + rr) * 512 + m0h + mt * 64 + lane] =
              __builtin_bit_cast(u16, (_Float16)tbuf[lane * 65 + rr]);
        __syncthreads();
      }
    }
  }

  // init release (full fence: pushes weights/XT/HB to MALL), RDY counter, acquire
  vm_drain();
  __syncthreads();
  if (tid == 0) { __threadfence(); atomicAdd(ctrl + FS_RDY, 1u); }
  flag_wait_ge(ctrl, FS_RDY, 32u, warp);
  __threadfence();   // one-time acquire: L1/L2 inv so normal XT/weight loads are fresh

  // ---- phase 0c: register-resident x: rows t=lane*8+r, cols m0h+warp*64.. ----
  uint4 xr4[64];
  {
    const u16* base = XT + (size_t)b * 262144 + m0h + warp * 64;
#pragma unroll
    for (int r = 0; r < 8; ++r) {
      const uint4* row = (const uint4*)(base + (size_t)(lane * 8 + r) * 512);
#pragma unroll
      for (int jj = 0; jj < 8; ++jj) xr4[r * 8 + jj] = row[jj];
    }
  }

  const int  r16 = lane & 15, q = lane >> 4, q8 = q * 8;
  const bool isA = (tb < 8), isW = (tb >= 8 && tb < 16);
  const int  W4 = ((tb < 8) ? tb : tb - 8) * 4 + warp;
  const int  n0 = W4 * 16;

  float biasA = 0.f, biasD = 0.f, biasI0 = 0.f, biasI1 = 0.f, biasI2 = 0.f,
        biasH0 = 0.f, biasH1 = 0.f, biasH2 = 0.f, biasO = 0.f;
  if (isA) {
    biasA = attn_b[n0 + r16]; biasD = comb_b[n0 + r16];
    biasI0 = b_ih[n0 + r16]; biasI1 = b_ih[512 + n0 + r16]; biasI2 = b_ih[1024 + n0 + r16];
    biasO = out_b[n0 + r16];
  }
  if (isW) {
    biasH0 = b_hh[n0 + r16]; biasH1 = b_hh[512 + n0 + r16]; biasH2 = b_hh[1024 + n0 + r16];
  }

  float hreg[4] = {0.f, 0.f, 0.f, 0.f};

  for (int t = 0; t < 512; ++t) {
    const u32 tok = (u32)(t + 1);

    if (isA) {
      flag_wait_ge(ctrl, FS_H, 8u * (u32)t, warp);   // ends in barrier
      stage_rows(HB + gb0 * 512, smem, tid);         // coherent h -> LDS
      __syncthreads();
      // stage A: S = [x(:,t) | h] @ attn_W^T + attn_b
      f32x4 acc = {0.f, 0.f, 0.f, 0.f};
      const u16* aXp = XT + (size_t)(gb0 + r16) * 262144 + (size_t)t * 512 + q8;
      const _Float16* aHl = ldsF + r16 * 520 + q8;
      const u16* bWp = AW + (size_t)(n0 + r16) * 1024 + q8;
#pragma unroll 4
      for (int k0 = 0; k0 < 512; k0 += 32)
        acc = MFMA(*(const f16x8*)(aXp + k0), *(const f16x8*)(bWp + k0), acc);
#pragma unroll 4
      for (int k0 = 0; k0 < 512; k0 += 32)
        acc = MFMA(*(const f16x8*)(aHl + k0), *(const f16x8*)(bWp + 512 + k0), acc);
#pragma unroll
      for (int i = 0; i < 4; ++i)
        stg_f32(Sf + (size_t)(gb0 + q * 4 + i) * 512 + n0 + r16, acc[i] + biasA);
      flag_add(ctrl, FS_S);
    } else if (isW) {
      flag_wait_ge(ctrl, FS_H, 8u * (u32)t, warp);
      stage_rows(HB + gb0 * 512, smem, tid);
      __syncthreads();
      // gh = h @ w_hh^T + b_hh (3 gate tiles, shared A-fragment)
      f32x4 a0 = {0.f,0.f,0.f,0.f}, a1 = {0.f,0.f,0.f,0.f}, a2 = {0.f,0.f,0.f,0.f};
      const _Float16* aHl = ldsF + r16 * 520 + q8;
      const u16* b0p = WHH + (size_t)(n0 + r16) * 512 + q8;
      const u16* b1p = WHH + (size_t)(512 + n0 + r16) * 512 + q8;
      const u16* b2p = WHH + (size_t)(1024 + n0 + r16) * 512 + q8;
#pragma unroll 4
      for (int k0 = 0; k0 < 512; k0 += 32) {
        f16x8 a = *(const f16x8*)(aHl + k0);
        a0 = MFMA(a, *(const f16x8*)(b0p + k0), a0);
        a1 = MFMA(a, *(const f16x8*)(b1p + k0), a1);
        a2 = MFMA(a, *(const f16x8*)(b2p + k0), a2);
      }
#pragma unroll
      for (int i = 0; i < 4; ++i) {
        const size_t ro = (size_t)(gb0 + q * 4 + i) * 1536;
        stg_f32(GH + ro + n0 + r16,        a0[i] + biasH0);
        stg_f32(GH + ro + 512 + n0 + r16,  a1[i] + biasH1);
        stg_f32(GH + ro + 1024 + n0 + r16, a2[i] + biasH2);
      }
      flag_add(ctrl, FS_GH);
    }

    // ---- all blocks: softmax (own batch) + applied partials from register x ----
    flag_wait_ge(ctrl, FS_S, 8u * tok, warp);
    {
      const int tc = 2 * tid;
      f32x2 sv = ldg_f32x2(Sf + (size_t)b * 512 + tc);   // coherent read
      float s0 = sv.x, s1 = sv.y;
      float mx = fmaxf(s0, s1);
#pragma unroll
      for (int off = 32; off; off >>= 1) mx = fmaxf(mx, __shfl_xor(mx, off, 64));
      if (lane == 0) rbuf[warp] = mx;
      __syncthreads();
      mx = fmaxf(fmaxf(rbuf[0], rbuf[1]), fmaxf(rbuf[2], rbuf[3]));
      float e0 = __expf(s0 - mx), e1 = __expf(s1 - mx);
      float sm = e0 + e1;
#pragma unroll
      for (int off = 32; off; off >>= 1) sm += __shfl_xor(sm, off, 64);
      if (lane == 0) rbuf[4 + warp] = sm;
      __syncthreads();
      sm = rbuf[4] + rbuf[5] + rbuf[6] + rbuf[7];
      const float inv = 1.f / sm;
      if ((tid >> 7) == half) {
        pLDS[tid & 127] = packh2(e0 * inv, e1 * inv);
      }
      __syncthreads();

      uint4 pz4[8];
      const uint4* pp = (const uint4*)pLDS + warp * 8;
#pragma unroll
      for (int jj = 0; jj < 8; ++jj) pz4[jj] = pp[jj];
      float accr[8];
#pragma unroll
      for (int r = 0; r < 8; ++r) {
        h2 sA = {(_Float16)0.f, (_Float16)0.f};
        h2 sB = {(_Float16)0.f, (_Float16)0.f};
#pragma unroll
        for (int jj = 0; jj < 8; ++jj) {
          uint4 xw = xr4[r * 8 + jj], pw = pz4[jj];
          sA = __builtin_bit_cast(h2, xw.x) * __builtin_bit_cast(h2, pw.x) + sA;
          sB = __builtin_bit_cast(h2, xw.y) * __builtin_bit_cast(h2, pw.y) + sB;
          sA = __builtin_bit_cast(h2, xw.z) * __builtin_bit_cast(h2, pw.z) + sA;
          sB = __builtin_bit_cast(h2, xw.w) * __builtin_bit_cast(h2, pw.w) + sB;
        }
        accr[r] = (float)sA.x + (float)sA.y + (float)sB.x + (float)sB.y;
      }
#pragma unroll
      for (int r = 0; r < 8; ++r) redbuf[warp * 512 + lane * 8 + r] = accr[r];
      __syncthreads();
      {
        float v0 = redbuf[tc]     + redbuf[512 + tc]     + redbuf[1024 + tc]     + redbuf[1536 + tc];
        float v1 = redbuf[tc + 1] + redbuf[512 + tc + 1] + redbuf[1024 + tc + 1] + redbuf[1536 + tc + 1];
        float* dst = (half ? AP1 : AP0) + (size_t)b * 512 + tc;
        f32x2 vv; vv.x = v0; vv.y = v1;
        stg_f32x2(dst, vv);
      }
      flag_add(ctrl, FS_C);
    }

    if (isA) {
      // stage D: g = relu([x(:,t) | applied] @ comb_W^T + comb_b); x-part first
      f32x4 acc = {0.f, 0.f, 0.f, 0.f};
      const u16* aXp = XT + (size_t)(gb0 + r16) * 262144 + (size_t)t * 512 + q8;
      const u16* bWp = CW + (size_t)(n0 + r16) * 1024 + q8;
#pragma unroll 4
      for (int k0 = 0; k0 < 512; k0 += 32)
        acc = MFMA(*(const f16x8*)(aXp + k0), *(const f16x8*)(bWp + k0), acc);
      flag_wait_ge(ctrl, FS_C, 32u * tok, warp);   // ends in barrier
      {  // stage applied = AP0+AP1 (16 coherent loads, ONE wait) -> f16 LDS rows
        const int row = tid >> 4, c = tid & 15;
        const float* g0 = AP0 + (size_t)(gb0 + row) * 512 + c * 32;
        const float* g1 = AP1 + (size_t)(gb0 + row) * 512 + c * 32;
        u32* dst = (u32*)(smem + row * 1040 + c * 64);
        u32x4 A[8], B[8];
        ldg_ap16(g0, g1, A, B);
#pragma unroll
        for (int k = 0; k < 8; ++k) {
          f32x4 s = __builtin_bit_cast(f32x4, A[k]) + __builtin_bit_cast(f32x4, B[k]);
          dst[2 * k]     = packh2(s[0], s[1]);
          dst[2 * k + 1] = packh2(s[2], s[3]);
        }
      }
      __syncthreads();
      const _Float16* aAl = ldsF + r16 * 520 + q8;
#pragma unroll 4
      for (int k0 = 0; k0 < 512; k0 += 32)
        acc = MFMA(*(const f16x8*)(aAl + k0), *(const f16x8*)(bWp + 512 + k0), acc);
#pragma unroll
      for (int i = 0; i < 4; ++i) {
        float g = fmaxf(acc[i] + biasD, 0.f);
        stg_u16(GB + (size_t)(gb0 + q * 4 + i) * 512 + n0 + r16,
                (u32)__builtin_bit_cast(u16, (_Float16)g));
      }
      flag_add(ctrl, FS_G);
      flag_wait_ge(ctrl, FS_G, 8u * tok, warp);
      stage_rows(GB + gb0 * 512, smem, tid);   // coherent g -> LDS
      __syncthreads();

      // stage EF: gi = g @ w_ih^T + b_ih (3 gates), then fused GRU pointwise
      f32x4 g0 = {0.f,0.f,0.f,0.f}, g1 = {0.f,0.f,0.f,0.f}, g2 = {0.f,0.f,0.f,0.f};
      const _Float16* aGl = ldsF + r16 * 520 + q8;
      const u16* w0p = WIH + (size_t)(n0 + r16) * 512 + q8;
      const u16* w1p = WIH + (size_t)(512 + n0 + r16) * 512 + q8;
      const u16* w2p = WIH + (size_t)(1024 + n0 + r16) * 512 + q8;
#pragma unroll 4
      for (int k0 = 0; k0 < 512; k0 += 32) {
        f16x8 a = *(const f16x8*)(aGl + k0);
        g0 = MFMA(a, *(const f16x8*)(w0p + k0), g0);
        g1 = MFMA(a, *(const f16x8*)(w1p + k0), g1);
        g2 = MFMA(a, *(const f16x8*)(w2p + k0), g2);
      }
      flag_wait_ge(ctrl, FS_GH, 8u * tok, warp);
      {
        const int j = n0 + r16;
        const float* q0p = GH + (size_t)(gb0 + q * 4 + 0) * 1536 + 512 + j;
        const float* q1p = GH + (size_t)(gb0 + q * 4 + 1) * 1536 + 512 + j;
        const float* q2p = GH + (size_t)(gb0 + q * 4 + 2) * 1536 + 512 + j;
        const float* q3p = GH + (size_t)(gb0 + q * 4 + 3) * 1536 + 512 + j;
        float ghr[4], ghz[4], ghn[4];
        ldg_gh12(q0p, q1p, q2p, q3p, ghr, ghz, ghn);   // 12 loads, ONE wait
#pragma unroll
        for (int i = 0; i < 4; ++i) {
          const int bi = gb0 + q * 4 + i;
          float gir = g0[i] + biasI0, giz = g1[i] + biasI1, gin = g2[i] + biasI2;
          float rg = sigmoidf_(gir + ghr[i]);
          float zg = sigmoidf_(giz + ghz[i]);
          float ng = tanhf_(gin + rg * ghn[i]);
          hreg[i] = (1.f - zg) * ng + zg * hreg[i];
          stg_u16(HB + (size_t)bi * 512 + j,
                  (u32)__builtin_bit_cast(u16, (_Float16)hreg[i]));
        }
      }
      flag_add(ctrl, FS_H);
    }
  }

  // ---- epilogue: out = h @ out_W^T + out_b ----
  if (isA) {
    flag_wait_ge(ctrl, FS_H, 8u * 512u, warp);
    stage_rows(HB + gb0 * 512, smem, tid);
    __syncthreads();
    f32x4 acc = {0.f, 0.f, 0.f, 0.f};
    const _Float16* aHl = ldsF + r16 * 520 + q8;
    const u16* bOp = OW + (size_t)(n0 + r16) * 512 + q8;
#pragma unroll 4
    for (int k0 = 0; k0 < 512; k0 += 32)
      acc = MFMA(*(const f16x8*)(aHl + k0), *(const f16x8*)(bOp + k0), acc);
#pragma unroll
    for (int i = 0; i < 4; ++i)
      out[(size_t)(gb0 + q * 4 + i) * 512 + n0 + r16] = acc[i] + biasO;
  }
}

extern "C" void kernel_launch(void* const* d_in, const int* in_sizes, int n_in,
                              void* d_out, int out_size, void* d_ws, size_t ws_size,
                              hipStream_t stream) {
  if (ws_size < (size_t)WS_NEED) return;
  rnn_fused<<<dim3(256), dim3(256), 0, stream>>>(
      (const float*)d_in[0], (const float*)d_in[1], (const float*)d_in[2],
      (const float*)d_in[3], (const float*)d_in[4], (const float*)d_in[5],
      (const float*)d_in[6], (const float*)d_in[7], (const float*)d_in[8],
      (const float*)d_in[9], (const float*)d_in[10],
      (float*)d_out, (char*)d_ws);
}

// Round 4
// 18650.209 us; speedup vs baseline: 1.2509x; 1.0789x over previous
//
#include <hip/hip_runtime.h>

// Persistent 8-team attention-GRU scan, register-resident x.
// Round-4 = round-3 resubmit (round-3 bench died in infra, not in kernel).
// XCD role partitioning: weights are team-independent and each warp's weight
// rows are fixed across all 512 steps, so co-locating same-ROLE blocks on an
// XCD makes the per-XCD weight working set fit the 4 MB L2 (was 5 MB+ for a
// whole team -> thrash to MALL every step):
//   XCD 0-3 (bid%8<4): isA blocks (AW+CW+WIH = 3.5 MB, L2-resident)
//   XCD 4-7:           isW blocks (WHH = 1.5 MB, L2-resident)
//   C-only blocks (no weight traffic) fill remaining slots.
// Pure (team,tb) permutation; all cross-block data is MALL-coherent, so
// correctness is independent of the actual dispatch->XCD mapping.
// Sync fabric unchanged from round 2 (counter flags, wave-0 polls,
// write-through sc0sc1 stores, batched coherent loads).

typedef unsigned short u16;
typedef unsigned int u32;
typedef _Float16 h2 __attribute__((ext_vector_type(2)));
typedef _Float16 f16x8 __attribute__((ext_vector_type(8)));
typedef float f32x4 __attribute__((ext_vector_type(4)));
typedef float f32x2 __attribute__((ext_vector_type(2)));
typedef u32 u32x4 __attribute__((ext_vector_type(4)));

#define MAGIC 0x13579BDFu

// ---- workspace layout (bytes) ----
#define OFF_AW   65536      // attn_W f16 [512][1024]
#define OFF_CW   1114112    // comb_W f16 [512][1024]
#define OFF_WIH  2162688    // w_ih  f16 [1536][512]
#define OFF_WHH  3735552    // w_hh  f16 [1536][512]
#define OFF_OW   5308416    // out_W f16 [512][512]
#define OFF_HB   5832704    // h f16 [128][512]
#define OFF_SF   5963776    // scores f32 [128][512]
#define OFF_AP0  6225920    // applied half0 partial f32 [128][512]
#define OFF_AP1  6488064    // applied half1 partial f32 [128][512]
#define OFF_GB   6750208    // g f16 [128][512]
#define OFF_GH   6881280    // gh f32 [128][1536] (flat)
#define OFF_XT   7667712    // x^T f16 [128 b][512 t][512 m]  64 MiB
#define WS_NEED  74776576

// per-stage counter slots (u32 index into per-team ctrl[1024]); 128B apart
#define FS_S   64
#define FS_C   96
#define FS_G   128
#define FS_GH  160
#define FS_H   192
#define FS_RDY 224

__device__ __forceinline__ float sigmoidf_(float v) { return 1.f / (1.f + __expf(-v)); }
__device__ __forceinline__ float tanhf_(float v) {
  v = fminf(fmaxf(v, -15.f), 15.f);
  float e2 = __expf(2.f * v);
  return (e2 - 1.f) / (e2 + 1.f);
}
__device__ __forceinline__ u32 packh2(float a, float b) {
  h2 v; v.x = (_Float16)a; v.y = (_Float16)b;
  return __builtin_bit_cast(u32, v);
}

__device__ __forceinline__ void vm_drain() { asm volatile("s_waitcnt vmcnt(0)" ::: "memory"); }

// ---- coherent (sc0 sc1) LOAD helpers ----
__device__ __forceinline__ f32x2 ldg_f32x2(const void* p) {
  f32x2 r;
  asm volatile("global_load_dwordx2 %0, %1, off sc0 sc1\n\ts_waitcnt vmcnt(0)"
               : "=v"(r) : "v"(p) : "memory");
  return r;
}
// 4 x dwordx4 from one base via offset immediates, one wait
__device__ __forceinline__ void ldg4x16_off(const void* p, u32x4& a, u32x4& b, u32x4& c, u32x4& d) {
  asm volatile(
      "global_load_dwordx4 %0, %4, off sc0 sc1\n\t"
      "global_load_dwordx4 %1, %4, off offset:16 sc0 sc1\n\t"
      "global_load_dwordx4 %2, %4, off offset:32 sc0 sc1\n\t"
      "global_load_dwordx4 %3, %4, off offset:48 sc0 sc1\n\t"
      "s_waitcnt vmcnt(0)"
      : "=&v"(a), "=&v"(b), "=&v"(c), "=&v"(d)
      : "v"(p) : "memory");
}
// 16 x dwordx4 (two 128B-contiguous rows), ONE wait.
__device__ __forceinline__ void ldg_ap16(const float* pa, const float* pb,
                                         u32x4 (&A)[8], u32x4 (&B)[8]) {
  asm volatile(
      "global_load_dwordx4 %0, %16, off sc0 sc1\n\t"
      "global_load_dwordx4 %1, %16, off offset:16 sc0 sc1\n\t"
      "global_load_dwordx4 %2, %16, off offset:32 sc0 sc1\n\t"
      "global_load_dwordx4 %3, %16, off offset:48 sc0 sc1\n\t"
      "global_load_dwordx4 %4, %16, off offset:64 sc0 sc1\n\t"
      "global_load_dwordx4 %5, %16, off offset:80 sc0 sc1\n\t"
      "global_load_dwordx4 %6, %16, off offset:96 sc0 sc1\n\t"
      "global_load_dwordx4 %7, %16, off offset:112 sc0 sc1\n\t"
      "global_load_dwordx4 %8, %17, off sc0 sc1\n\t"
      "global_load_dwordx4 %9, %17, off offset:16 sc0 sc1\n\t"
      "global_load_dwordx4 %10, %17, off offset:32 sc0 sc1\n\t"
      "global_load_dwordx4 %11, %17, off offset:48 sc0 sc1\n\t"
      "global_load_dwordx4 %12, %17, off offset:64 sc0 sc1\n\t"
      "global_load_dwordx4 %13, %17, off offset:80 sc0 sc1\n\t"
      "global_load_dwordx4 %14, %17, off offset:96 sc0 sc1\n\t"
      "global_load_dwordx4 %15, %17, off offset:112 sc0 sc1\n\t"
      "s_waitcnt vmcnt(0)"
      : "=&v"(A[0]), "=&v"(A[1]), "=&v"(A[2]), "=&v"(A[3]),
        "=&v"(A[4]), "=&v"(A[5]), "=&v"(A[6]), "=&v"(A[7]),
        "=&v"(B[0]), "=&v"(B[1]), "=&v"(B[2]), "=&v"(B[3]),
        "=&v"(B[4]), "=&v"(B[5]), "=&v"(B[6]), "=&v"(B[7])
      : "v"(pa), "v"(pb) : "memory");
}
// 12 GH gate values (r/z/n for 4 rows) via one base per row (+-2048B offsets), ONE wait
__device__ __forceinline__ void ldg_gh12(const float* q0, const float* q1,
                                         const float* q2, const float* q3,
                                         float (&rr)[4], float (&zz)[4], float (&nn)[4]) {
  asm volatile(
      "global_load_dword %0, %12, off offset:-2048 sc0 sc1\n\t"
      "global_load_dword %4, %12, off sc0 sc1\n\t"
      "global_load_dword %8, %12, off offset:2048 sc0 sc1\n\t"
      "global_load_dword %1, %13, off offset:-2048 sc0 sc1\n\t"
      "global_load_dword %5, %13, off sc0 sc1\n\t"
      "global_load_dword %9, %13, off offset:2048 sc0 sc1\n\t"
      "global_load_dword %2, %14, off offset:-2048 sc0 sc1\n\t"
      "global_load_dword %6, %14, off sc0 sc1\n\t"
      "global_load_dword %10, %14, off offset:2048 sc0 sc1\n\t"
      "global_load_dword %3, %15, off offset:-2048 sc0 sc1\n\t"
      "global_load_dword %7, %15, off sc0 sc1\n\t"
      "global_load_dword %11, %15, off offset:2048 sc0 sc1\n\t"
      "s_waitcnt vmcnt(0)"
      : "=&v"(rr[0]), "=&v"(rr[1]), "=&v"(rr[2]), "=&v"(rr[3]),
        "=&v"(zz[0]), "=&v"(zz[1]), "=&v"(zz[2]), "=&v"(zz[3]),
        "=&v"(nn[0]), "=&v"(nn[1]), "=&v"(nn[2]), "=&v"(nn[3])
      : "v"(q0), "v"(q1), "v"(q2), "v"(q3) : "memory");
}

// ---- coherent (sc0 sc1) WRITE-THROUGH store helpers ----
__device__ __forceinline__ void stg_f32(float* p, float v) {
  asm volatile("global_store_dword %0, %1, off sc0 sc1" :: "v"(p), "v"(v) : "memory");
}
__device__ __forceinline__ void stg_f32x2(float* p, f32x2 v) {
  asm volatile("global_store_dwordx2 %0, %1, off sc0 sc1" :: "v"(p), "v"(v) : "memory");
}
__device__ __forceinline__ void stg_u16(u16* p, u32 v) {
  asm volatile("global_store_short %0, %1, off sc0 sc1" :: "v"(p), "v"(v) : "memory");
}

// producer: drain write-through stores (vmcnt ack = at coherence point),
// barrier orders all waves' drains before tid0's counter bump.
__device__ __forceinline__ void flag_add(u32* ctrl, int fs) {
  vm_drain();
  __syncthreads();
  if (threadIdx.x == 0) atomicAdd(ctrl + fs, 1u);
}
// consumer: wave 0 polls ONE dword, everyone else parks at the barrier.
__device__ __forceinline__ void flag_wait_ge(u32* ctrl, int fs, u32 target, int warp) {
  if (warp == 0) {
    u32 v;
    do {
      v = __hip_atomic_load(ctrl + fs, __ATOMIC_RELAXED, __HIP_MEMORY_SCOPE_AGENT);
    } while (v < target);
  }
  __syncthreads();
}

// stage 16 rows x 512 f16 (coherent loads) -> LDS rows, stride 520 f16 (1040 B)
__device__ __forceinline__ void stage_rows(const u16* gsrc, char* lds, int tid) {
  const int row = tid >> 4, c = tid & 15;
  const u16* g = gsrc + row * 512 + c * 32;
  u32x4 a, b, cc, d;
  ldg4x16_off(g, a, b, cc, d);
  u32x4* dst = (u32x4*)(lds + row * 1040 + c * 64);
  dst[0] = a; dst[1] = b; dst[2] = cc; dst[3] = d;
}

#define MFMA(a, b, c) __builtin_amdgcn_mfma_f32_16x16x32_f16((a), (b), (c), 0, 0, 0)

extern "C" __global__ void __launch_bounds__(256, 1)
rnn_fused(const float* __restrict__ x, const float* __restrict__ attn_W,
          const float* __restrict__ attn_b, const float* __restrict__ comb_W,
          const float* __restrict__ comb_b, const float* __restrict__ w_ih,
          const float* __restrict__ w_hh, const float* __restrict__ b_ih,
          const float* __restrict__ b_hh, const float* __restrict__ out_W,
          const float* __restrict__ out_b, float* __restrict__ out,
          char* __restrict__ ws)
{
  const int tid  = threadIdx.x;
  const int lane = tid & 63;
  const int warp = tid >> 6;

  // ---- XCD role partition: (team, tb) from blockIdx, assuming XCD = bid%8 ----
  // XCD 0-3 slots 0-15: isA (tb 0-7), two teams per XCD.
  // XCD 4-7 slots 0-15: isW (tb 8-15), two teams per XCD.
  // all XCDs slots 16-31: C-only (tb 16-31, no weight traffic), team = XCD.
  int team, tb;
  {
    const int r = blockIdx.x & 7;    // presumed XCD
    const int s = blockIdx.x >> 3;   // slot on that XCD
    if (s < 16) {
      if (r < 4) { team = r * 2 + (s >> 3); tb = s & 7; }
      else       { team = (r - 4) * 2 + (s >> 3); tb = 8 + (s & 7); }
    } else {
      team = r; tb = s;
    }
  }

  const int tt   = tb * 256 + tid;      // team thread id
  const int gb0  = team * 16;
  const int lb   = tb >> 1;             // pair index -> batch
  const int half = tb & 1;              // m-half of x held by this block
  const int b    = gb0 + lb;            // this block's batch (x holder / stage C)
  const int m0h  = half * 256;

  u32* ctrl = (u32*)ws + team * 1024;   // 4 KB per team

  u16*   AW  = (u16*)(ws + OFF_AW);
  u16*   CW  = (u16*)(ws + OFF_CW);
  u16*   WIH = (u16*)(ws + OFF_WIH);
  u16*   WHH = (u16*)(ws + OFF_WHH);
  u16*   OW  = (u16*)(ws + OFF_OW);
  u16*   HB  = (u16*)(ws + OFF_HB);
  float* Sf  = (float*)(ws + OFF_SF);
  float* AP0 = (float*)(ws + OFF_AP0);
  float* AP1 = (float*)(ws + OFF_AP1);
  u16*   GB  = (u16*)(ws + OFF_GB);
  float* GH  = (float*)(ws + OFF_GH);
  u16*   XT  = (u16*)(ws + OFF_XT);

  __shared__ char smem[16704];
  float*     tbuf   = (float*)smem;           // [64][65] f32, init transpose only
  u32*       pLDS   = (u32*)smem;             // [128] packed f16 p-pairs (stage C)
  float*     redbuf = (float*)(smem + 512);   // [4][512] stage C partials
  float*     rbuf   = (float*)(smem + 8704);  // [8] softmax reduce scratch
  _Float16*  ldsF   = (_Float16*)smem;        // staged fragments, row stride 520

  // ---- init handshake (per team): block tb==0 zeroes ctrl, sets magic ----
  if (tb == 0) {
    for (int i = 1 + tid; i < 1024; i += 256) ctrl[i] = 0u;
    __syncthreads();
    if (tid == 0) { __threadfence(); atomicExch(ctrl, MAGIC); }
  }
  if (tid == 0) {
    while (__hip_atomic_load(ctrl, __ATOMIC_RELAXED, __HIP_MEMORY_SCOPE_AGENT) != MAGIC) {}
    __threadfence();
  }
  __syncthreads();

  // ---- phase 0a: weights -> f16 (team-redundant, same-value benign races) ----
  for (int i = tt; i < 512 * 1024; i += 8192) AW[i]  = __builtin_bit_cast(u16, (_Float16)attn_W[i]);
  for (int i = tt; i < 512 * 1024; i += 8192) CW[i]  = __builtin_bit_cast(u16, (_Float16)comb_W[i]);
  for (int i = tt; i < 1536 * 512; i += 8192) WIH[i] = __builtin_bit_cast(u16, (_Float16)w_ih[i]);
  for (int i = tt; i < 1536 * 512; i += 8192) WHH[i] = __builtin_bit_cast(u16, (_Float16)w_hh[i]);
  for (int i = tt; i < 512 * 512;  i += 8192) OW[i]  = __builtin_bit_cast(u16, (_Float16)out_W[i]);
  HB[(size_t)gb0 * 512 + tt] = 0;   // h0 = 0

  // ---- phase 0b: transpose this block's m-half of x[b] into XT[b][t][m] (f16) ----
  {
    const float* xb  = x  + (size_t)b * 512 * 512;
    u16*         xtB = XT + (size_t)b * 512 * 512;
    for (int mt = 0; mt < 4; ++mt) {
      for (int ct = 0; ct < 8; ++ct) {
        for (int rr = warp; rr < 64; rr += 4)
          tbuf[rr * 65 + lane] = xb[(size_t)(m0h + mt * 64 + rr) * 512 + ct * 64 + lane];
        __syncthreads();
        for (int rr = warp; rr < 64; rr += 4)
          xtB[(size_t)(ct * 64 + rr) * 512 + m0h + mt * 64 + lane] =
              __builtin_bit_cast(u16, (_Float16)tbuf[lane * 65 + rr]);
        __syncthreads();
      }
    }
  }

  // init release (full fence: pushes weights/XT/HB to MALL), RDY counter, acquire
  vm_drain();
  __syncthreads();
  if (tid == 0) { __threadfence(); atomicAdd(ctrl + FS_RDY, 1u); }
  flag_wait_ge(ctrl, FS_RDY, 32u, warp);
  __threadfence();   // one-time acquire: L1/L2 inv so normal XT/weight loads are fresh

  // ---- phase 0c: register-resident x: rows t=lane*8+r, cols m0h+warp*64.. ----
  uint4 xr4[64];
  {
    const u16* base = XT + (size_t)b * 262144 + m0h + warp * 64;
#pragma unroll
    for (int r = 0; r < 8; ++r) {
      const uint4* row = (const uint4*)(base + (size_t)(lane * 8 + r) * 512);
#pragma unroll
      for (int jj = 0; jj < 8; ++jj) xr4[r * 8 + jj] = row[jj];
    }
  }

  const int  r16 = lane & 15, q = lane >> 4, q8 = q * 8;
  const bool isA = (tb < 8), isW = (tb >= 8 && tb < 16);
  const int  W4 = ((tb < 8) ? tb : tb - 8) * 4 + warp;
  const int  n0 = W4 * 16;

  float biasA = 0.f, biasD = 0.f, biasI0 = 0.f, biasI1 = 0.f, biasI2 = 0.f,
        biasH0 = 0.f, biasH1 = 0.f, biasH2 = 0.f, biasO = 0.f;
  if (isA) {
    biasA = attn_b[n0 + r16]; biasD = comb_b[n0 + r16];
    biasI0 = b_ih[n0 + r16]; biasI1 = b_ih[512 + n0 + r16]; biasI2 = b_ih[1024 + n0 + r16];
    biasO = out_b[n0 + r16];
  }
  if (isW) {
    biasH0 = b_hh[n0 + r16]; biasH1 = b_hh[512 + n0 + r16]; biasH2 = b_hh[1024 + n0 + r16];
  }

  float hreg[4] = {0.f, 0.f, 0.f, 0.f};

  for (int t = 0; t < 512; ++t) {
    const u32 tok = (u32)(t + 1);

    if (isA) {
      flag_wait_ge(ctrl, FS_H, 8u * (u32)t, warp);   // ends in barrier
      stage_rows(HB + gb0 * 512, smem, tid);         // coherent h -> LDS
      __syncthreads();
      // stage A: S = [x(:,t) | h] @ attn_W^T + attn_b
      f32x4 acc = {0.f, 0.f, 0.f, 0.f};
      const u16* aXp = XT + (size_t)(gb0 + r16) * 262144 + (size_t)t * 512 + q8;
      const _Float16* aHl = ldsF + r16 * 520 + q8;
      const u16* bWp = AW + (size_t)(n0 + r16) * 1024 + q8;
#pragma unroll 4
      for (int k0 = 0; k0 < 512; k0 += 32)
        acc = MFMA(*(const f16x8*)(aXp + k0), *(const f16x8*)(bWp + k0), acc);
#pragma unroll 4
      for (int k0 = 0; k0 < 512; k0 += 32)
        acc = MFMA(*(const f16x8*)(aHl + k0), *(const f16x8*)(bWp + 512 + k0), acc);
#pragma unroll
      for (int i = 0; i < 4; ++i)
        stg_f32(Sf + (size_t)(gb0 + q * 4 + i) * 512 + n0 + r16, acc[i] + biasA);
      flag_add(ctrl, FS_S);
    } else if (isW) {
      flag_wait_ge(ctrl, FS_H, 8u * (u32)t, warp);
      stage_rows(HB + gb0 * 512, smem, tid);
      __syncthreads();
      // gh = h @ w_hh^T + b_hh (3 gate tiles, shared A-fragment)
      f32x4 a0 = {0.f,0.f,0.f,0.f}, a1 = {0.f,0.f,0.f,0.f}, a2 = {0.f,0.f,0.f,0.f};
      const _Float16* aHl = ldsF + r16 * 520 + q8;
      const u16* b0p = WHH + (size_t)(n0 + r16) * 512 + q8;
      const u16* b1p = WHH + (size_t)(512 + n0 + r16) * 512 + q8;
      const u16* b2p = WHH + (size_t)(1024 + n0 + r16) * 512 + q8;
#pragma unroll 4
      for (int k0 = 0; k0 < 512; k0 += 32) {
        f16x8 a = *(const f16x8*)(aHl + k0);
        a0 = MFMA(a, *(const f16x8*)(b0p + k0), a0);
        a1 = MFMA(a, *(const f16x8*)(b1p + k0), a1);
        a2 = MFMA(a, *(const f16x8*)(b2p + k0), a2);
      }
#pragma unroll
      for (int i = 0; i < 4; ++i) {
        const size_t ro = (size_t)(gb0 + q * 4 + i) * 1536;
        stg_f32(GH + ro + n0 + r16,        a0[i] + biasH0);
        stg_f32(GH + ro + 512 + n0 + r16,  a1[i] + biasH1);
        stg_f32(GH + ro + 1024 + n0 + r16, a2[i] + biasH2);
      }
      flag_add(ctrl, FS_GH);
    }

    // ---- all blocks: softmax (own batch) + applied partials from register x ----
    flag_wait_ge(ctrl, FS_S, 8u * tok, warp);
    {
      const int tc = 2 * tid;
      f32x2 sv = ldg_f32x2(Sf + (size_t)b * 512 + tc);   // coherent read
      float s0 = sv.x, s1 = sv.y;
      float mx = fmaxf(s0, s1);
#pragma unroll
      for (int off = 32; off; off >>= 1) mx = fmaxf(mx, __shfl_xor(mx, off, 64));
      if (lane == 0) rbuf[warp] = mx;
      __syncthreads();
      mx = fmaxf(fmaxf(rbuf[0], rbuf[1]), fmaxf(rbuf[2], rbuf[3]));
      float e0 = __expf(s0 - mx), e1 = __expf(s1 - mx);
      float sm = e0 + e1;
#pragma unroll
      for (int off = 32; off; off >>= 1) sm += __shfl_xor(sm, off, 64);
      if (lane == 0) rbuf[4 + warp] = sm;
      __syncthreads();
      sm = rbuf[4] + rbuf[5] + rbuf[6] + rbuf[7];
      const float inv = 1.f / sm;
      if ((tid >> 7) == half) {
        pLDS[tid & 127] = packh2(e0 * inv, e1 * inv);
      }
      __syncthreads();

      uint4 pz4[8];
      const uint4* pp = (const uint4*)pLDS + warp * 8;
#pragma unroll
      for (int jj = 0; jj < 8; ++jj) pz4[jj] = pp[jj];
      float accr[8];
#pragma unroll
      for (int r = 0; r < 8; ++r) {
        h2 sA = {(_Float16)0.f, (_Float16)0.f};
        h2 sB = {(_Float16)0.f, (_Float16)0.f};
#pragma unroll
        for (int jj = 0; jj < 8; ++jj) {
          uint4 xw = xr4[r * 8 + jj], pw = pz4[jj];
          sA = __builtin_bit_cast(h2, xw.x) * __builtin_bit_cast(h2, pw.x) + sA;
          sB = __builtin_bit_cast(h2, xw.y) * __builtin_bit_cast(h2, pw.y) + sB;
          sA = __builtin_bit_cast(h2, xw.z) * __builtin_bit_cast(h2, pw.z) + sA;
          sB = __builtin_bit_cast(h2, xw.w) * __builtin_bit_cast(h2, pw.w) + sB;
        }
        accr[r] = (float)sA.x + (float)sA.y + (float)sB.x + (float)sB.y;
      }
#pragma unroll
      for (int r = 0; r < 8; ++r) redbuf[warp * 512 + lane * 8 + r] = accr[r];
      __syncthreads();
      {
        float v0 = redbuf[tc]     + redbuf[512 + tc]     + redbuf[1024 + tc]     + redbuf[1536 + tc];
        float v1 = redbuf[tc + 1] + redbuf[512 + tc + 1] + redbuf[1024 + tc + 1] + redbuf[1536 + tc + 1];
        float* dst = (half ? AP1 : AP0) + (size_t)b * 512 + tc;
        f32x2 vv; vv.x = v0; vv.y = v1;
        stg_f32x2(dst, vv);
      }
      flag_add(ctrl, FS_C);
    }

    if (isA) {
      // stage D: g = relu([x(:,t) | applied] @ comb_W^T + comb_b); x-part first
      f32x4 acc = {0.f, 0.f, 0.f, 0.f};
      const u16* aXp = XT + (size_t)(gb0 + r16) * 262144 + (size_t)t * 512 + q8;
      const u16* bWp = CW + (size_t)(n0 + r16) * 1024 + q8;
#pragma unroll 4
      for (int k0 = 0; k0 < 512; k0 += 32)
        acc = MFMA(*(const f16x8*)(aXp + k0), *(const f16x8*)(bWp + k0), acc);
      flag_wait_ge(ctrl, FS_C, 32u * tok, warp);   // ends in barrier
      {  // stage applied = AP0+AP1 (16 coherent loads, ONE wait) -> f16 LDS rows
        const int row = tid >> 4, c = tid & 15;
        const float* g0 = AP0 + (size_t)(gb0 + row) * 512 + c * 32;
        const float* g1 = AP1 + (size_t)(gb0 + row) * 512 + c * 32;
        u32* dst = (u32*)(smem + row * 1040 + c * 64);
        u32x4 A[8], B[8];
        ldg_ap16(g0, g1, A, B);
#pragma unroll
        for (int k = 0; k < 8; ++k) {
          f32x4 s = __builtin_bit_cast(f32x4, A[k]) + __builtin_bit_cast(f32x4, B[k]);
          dst[2 * k]     = packh2(s[0], s[1]);
          dst[2 * k + 1] = packh2(s[2], s[3]);
        }
      }
      __syncthreads();
      const _Float16* aAl = ldsF + r16 * 520 + q8;
#pragma unroll 4
      for (int k0 = 0; k0 < 512; k0 += 32)
        acc = MFMA(*(const f16x8*)(aAl + k0), *(const f16x8*)(bWp + 512 + k0), acc);
#pragma unroll
      for (int i = 0; i < 4; ++i) {
        float g = fmaxf(acc[i] + biasD, 0.f);
        stg_u16(GB + (size_t)(gb0 + q * 4 + i) * 512 + n0 + r16,
                (u32)__builtin_bit_cast(u16, (_Float16)g));
      }
      flag_add(ctrl, FS_G);
      flag_wait_ge(ctrl, FS_G, 8u * tok, warp);
      stage_rows(GB + gb0 * 512, smem, tid);   // coherent g -> LDS
      __syncthreads();

      // stage EF: gi = g @ w_ih^T + b_ih (3 gates), then fused GRU pointwise
      f32x4 g0 = {0.f,0.f,0.f,0.f}, g1 = {0.f,0.f,0.f,0.f}, g2 = {0.f,0.f,0.f,0.f};
      const _Float16* aGl = ldsF + r16 * 520 + q8;
      const u16* w0p = WIH + (size_t)(n0 + r16) * 512 + q8;
      const u16* w1p = WIH + (size_t)(512 + n0 + r16) * 512 + q8;
      const u16* w2p = WIH + (size_t)(1024 + n0 + r16) * 512 + q8;
#pragma unroll 4
      for (int k0 = 0; k0 < 512; k0 += 32) {
        f16x8 a = *(const f16x8*)(aGl + k0);
        g0 = MFMA(a, *(const f16x8*)(w0p + k0), g0);
        g1 = MFMA(a, *(const f16x8*)(w1p + k0), g1);
        g2 = MFMA(a, *(const f16x8*)(w2p + k0), g2);
      }
      flag_wait_ge(ctrl, FS_GH, 8u * tok, warp);
      {
        const int j = n0 + r16;
        const float* q0p = GH + (size_t)(gb0 + q * 4 + 0) * 1536 + 512 + j;
        const float* q1p = GH + (size_t)(gb0 + q * 4 + 1) * 1536 + 512 + j;
        const float* q2p = GH + (size_t)(gb0 + q * 4 + 2) * 1536 + 512 + j;
        const float* q3p = GH + (size_t)(gb0 + q * 4 + 3) * 1536 + 512 + j;
        float ghr[4], ghz[4], ghn[4];
        ldg_gh12(q0p, q1p, q2p, q3p, ghr, ghz, ghn);   // 12 loads, ONE wait
#pragma unroll
        for (int i = 0; i < 4; ++i) {
          const int bi = gb0 + q * 4 + i;
          float gir = g0[i] + biasI0, giz = g1[i] + biasI1, gin = g2[i] + biasI2;
          float rg = sigmoidf_(gir + ghr[i]);
          float zg = sigmoidf_(giz + ghz[i]);
          float ng = tanhf_(gin + rg * ghn[i]);
          hreg[i] = (1.f - zg) * ng + zg * hreg[i];
          stg_u16(HB + (size_t)bi * 512 + j,
                  (u32)__builtin_bit_cast(u16, (_Float16)hreg[i]));
        }
      }
      flag_add(ctrl, FS_H);
    }
  }

  // ---- epilogue: out = h @ out_W^T + out_b ----
  if (isA) {
    flag_wait_ge(ctrl, FS_H, 8u * 512u, warp);
    stage_rows(HB + gb0 * 512, smem, tid);
    __syncthreads();
    f32x4 acc = {0.f, 0.f, 0.f, 0.f};
    const _Float16* aHl = ldsF + r16 * 520 + q8;
    const u16* bOp = OW + (size_t)(n0 + r16) * 512 + q8;
#pragma unroll 4
    for (int k0 = 0; k0 < 512; k0 += 32)
      acc = MFMA(*(const f16x8*)(aHl + k0), *(const f16x8*)(bOp + k0), acc);
#pragma unroll
    for (int i = 0; i < 4; ++i)
      out[(size_t)(gb0 + q * 4 + i) * 512 + n0 + r16] = acc[i] + biasO;
  }
}

extern "C" void kernel_launch(void* const* d_in, const int* in_sizes, int n_in,
                              void* d_out, int out_size, void* d_ws, size_t ws_size,
                              hipStream_t stream) {
  if (ws_size < (size_t)WS_NEED) return;
  rnn_fused<<<dim3(256), dim3(256), 0, stream>>>(
      (const float*)d_in[0], (const float*)d_in[1], (const float*)d_in[2],
      (const float*)d_in[3], (const float*)d_in[4], (const float*)d_in[5],
      (const float*)d_in[6], (const float*)d_in[7], (const float*)d_in[8],
      (const float*)d_in[9], (const float*)d_in[10],
      (float*)d_out, (char*)d_ws);
}

// Round 6
// 17708.682 us; speedup vs baseline: 1.3174x; 1.0532x over previous
//
#include <hip/hip_runtime.h>

// Persistent 8-team attention-GRU scan, register-resident x.
// Round-6: x(:,t) LDS prefetch, WAITED-ISSUE variant.
//   Round-5's no-wait prefetch NaN'd: inline-asm loads with no s_waitcnt
//   return "valid" outputs the compiler may copy (loop PHI/backedge moves)
//   before data lands -> garbage. Fix: fuse the x(:,t+1) loads with the Sf
//   score load in ONE asm block ending in vmcnt(0) -- registers valid at asm
//   exit, compiler free to move them. Costs ~0.3us extra wait in the softmax
//   phase (HBM vs MALL latency, overlapped); still removes the 2x per-step
//   XT demand-miss streams from both MFMA K-loops (x read from LDS).
// Round-4 XCD role partition kept (CONFIRMED: FETCH 11.4GB -> 1.5GB).
// Sync fabric unchanged from round 2 (counter flags, wave-0 polls,
// write-through sc0sc1 stores, batched coherent loads).

typedef unsigned short u16;
typedef unsigned int u32;
typedef _Float16 h2 __attribute__((ext_vector_type(2)));
typedef _Float16 f16x8 __attribute__((ext_vector_type(8)));
typedef float f32x4 __attribute__((ext_vector_type(4)));
typedef float f32x2 __attribute__((ext_vector_type(2)));
typedef u32 u32x4 __attribute__((ext_vector_type(4)));

#define MAGIC 0x13579BDFu

// ---- workspace layout (bytes) ----
#define OFF_AW   65536      // attn_W f16 [512][1024]
#define OFF_CW   1114112    // comb_W f16 [512][1024]
#define OFF_WIH  2162688    // w_ih  f16 [1536][512]
#define OFF_WHH  3735552    // w_hh  f16 [1536][512]
#define OFF_OW   5308416    // out_W f16 [512][512]
#define OFF_HB   5832704    // h f16 [128][512]
#define OFF_SF   5963776    // scores f32 [128][512]
#define OFF_AP0  6225920    // applied half0 partial f32 [128][512]
#define OFF_AP1  6488064    // applied half1 partial f32 [128][512]
#define OFF_GB   6750208    // g f16 [128][512]
#define OFF_GH   6881280    // gh f32 [128][1536] (flat)
#define OFF_XT   7667712    // x^T f16 [128 b][512 t][512 m]  64 MiB
#define WS_NEED  74776576

// per-stage counter slots (u32 index into per-team ctrl[1024]); 128B apart
#define FS_S   64
#define FS_C   96
#define FS_G   128
#define FS_GH  160
#define FS_H   192
#define FS_RDY 224

__device__ __forceinline__ float sigmoidf_(float v) { return 1.f / (1.f + __expf(-v)); }
__device__ __forceinline__ float tanhf_(float v) {
  v = fminf(fmaxf(v, -15.f), 15.f);
  float e2 = __expf(2.f * v);
  return (e2 - 1.f) / (e2 + 1.f);
}
__device__ __forceinline__ u32 packh2(float a, float b) {
  h2 v; v.x = (_Float16)a; v.y = (_Float16)b;
  return __builtin_bit_cast(u32, v);
}

__device__ __forceinline__ void vm_drain() { asm volatile("s_waitcnt vmcnt(0)" ::: "memory"); }

// ---- coherent (sc0 sc1) LOAD helpers ----
__device__ __forceinline__ f32x2 ldg_f32x2(const void* p) {
  f32x2 r;
  asm volatile("global_load_dwordx2 %0, %1, off sc0 sc1\n\ts_waitcnt vmcnt(0)"
               : "=v"(r) : "v"(p) : "memory");
  return r;
}
// 4 x dwordx4 from one base via offset immediates, one wait (coherent)
__device__ __forceinline__ void ldg4x16_off(const void* p, u32x4& a, u32x4& b, u32x4& c, u32x4& d) {
  asm volatile(
      "global_load_dwordx4 %0, %4, off sc0 sc1\n\t"
      "global_load_dwordx4 %1, %4, off offset:16 sc0 sc1\n\t"
      "global_load_dwordx4 %2, %4, off offset:32 sc0 sc1\n\t"
      "global_load_dwordx4 %3, %4, off offset:48 sc0 sc1\n\t"
      "s_waitcnt vmcnt(0)"
      : "=&v"(a), "=&v"(b), "=&v"(c), "=&v"(d)
      : "v"(p) : "memory");
}
// 4 x dwordx4 NORMAL-cached loads, WAITED (values valid at exit).
__device__ __forceinline__ void ldg4x16_wait(const void* p, u32x4& a, u32x4& b, u32x4& c, u32x4& d) {
  asm volatile(
      "global_load_dwordx4 %0, %4, off\n\t"
      "global_load_dwordx4 %1, %4, off offset:16\n\t"
      "global_load_dwordx4 %2, %4, off offset:32\n\t"
      "global_load_dwordx4 %3, %4, off offset:48\n\t"
      "s_waitcnt vmcnt(0)"
      : "=&v"(a), "=&v"(b), "=&v"(c), "=&v"(d)
      : "v"(p) : "memory");
}
// fused: coherent Sf dwordx2 + 4 normal x-prefetch dwordx4, ONE wait.
// All outputs architecturally valid at asm exit (safe for compiler moves).
__device__ __forceinline__ void ldg_sf_x(const float* sp, const u16* xp, f32x2& sv,
                                         u32x4& a, u32x4& b, u32x4& c, u32x4& d) {
  asm volatile(
      "global_load_dwordx2 %0, %5, off sc0 sc1\n\t"
      "global_load_dwordx4 %1, %6, off\n\t"
      "global_load_dwordx4 %2, %6, off offset:16\n\t"
      "global_load_dwordx4 %3, %6, off offset:32\n\t"
      "global_load_dwordx4 %4, %6, off offset:48\n\t"
      "s_waitcnt vmcnt(0)"
      : "=&v"(sv), "=&v"(a), "=&v"(b), "=&v"(c), "=&v"(d)
      : "v"(sp), "v"(xp) : "memory");
}
// 16 x dwordx4 (two 128B-contiguous rows), ONE wait.
__device__ __forceinline__ void ldg_ap16(const float* pa, const float* pb,
                                         u32x4 (&A)[8], u32x4 (&B)[8]) {
  asm volatile(
      "global_load_dwordx4 %0, %16, off sc0 sc1\n\t"
      "global_load_dwordx4 %1, %16, off offset:16 sc0 sc1\n\t"
      "global_load_dwordx4 %2, %16, off offset:32 sc0 sc1\n\t"
      "global_load_dwordx4 %3, %16, off offset:48 sc0 sc1\n\t"
      "global_load_dwordx4 %4, %16, off offset:64 sc0 sc1\n\t"
      "global_load_dwordx4 %5, %16, off offset:80 sc0 sc1\n\t"
      "global_load_dwordx4 %6, %16, off offset:96 sc0 sc1\n\t"
      "global_load_dwordx4 %7, %16, off offset:112 sc0 sc1\n\t"
      "global_load_dwordx4 %8, %17, off sc0 sc1\n\t"
      "global_load_dwordx4 %9, %17, off offset:16 sc0 sc1\n\t"
      "global_load_dwordx4 %10, %17, off offset:32 sc0 sc1\n\t"
      "global_load_dwordx4 %11, %17, off offset:48 sc0 sc1\n\t"
      "global_load_dwordx4 %12, %17, off offset:64 sc0 sc1\n\t"
      "global_load_dwordx4 %13, %17, off offset:80 sc0 sc1\n\t"
      "global_load_dwordx4 %14, %17, off offset:96 sc0 sc1\n\t"
      "global_load_dwordx4 %15, %17, off offset:112 sc0 sc1\n\t"
      "s_waitcnt vmcnt(0)"
      : "=&v"(A[0]), "=&v"(A[1]), "=&v"(A[2]), "=&v"(A[3]),
        "=&v"(A[4]), "=&v"(A[5]), "=&v"(A[6]), "=&v"(A[7]),
        "=&v"(B[0]), "=&v"(B[1]), "=&v"(B[2]), "=&v"(B[3]),
        "=&v"(B[4]), "=&v"(B[5]), "=&v"(B[6]), "=&v"(B[7])
      : "v"(pa), "v"(pb) : "memory");
}
// 12 GH gate values (r/z/n for 4 rows) via one base per row (+-2048B offsets), ONE wait
__device__ __forceinline__ void ldg_gh12(const float* q0, const float* q1,
                                         const float* q2, const float* q3,
                                         float (&rr)[4], float (&zz)[4], float (&nn)[4]) {
  asm volatile(
      "global_load_dword %0, %12, off offset:-2048 sc0 sc1\n\t"
      "global_load_dword %4, %12, off sc0 sc1\n\t"
      "global_load_dword %8, %12, off offset:2048 sc0 sc1\n\t"
      "global_load_dword %1, %13, off offset:-2048 sc0 sc1\n\t"
      "global_load_dword %5, %13, off sc0 sc1\n\t"
      "global_load_dword %9, %13, off offset:2048 sc0 sc1\n\t"
      "global_load_dword %2, %14, off offset:-2048 sc0 sc1\n\t"
      "global_load_dword %6, %14, off sc0 sc1\n\t"
      "global_load_dword %10, %14, off offset:2048 sc0 sc1\n\t"
      "global_load_dword %3, %15, off offset:-2048 sc0 sc1\n\t"
      "global_load_dword %7, %15, off sc0 sc1\n\t"
      "global_load_dword %11, %15, off offset:2048 sc0 sc1\n\t"
      "s_waitcnt vmcnt(0)"
      : "=&v"(rr[0]), "=&v"(rr[1]), "=&v"(rr[2]), "=&v"(rr[3]),
        "=&v"(zz[0]), "=&v"(zz[1]), "=&v"(zz[2]), "=&v"(zz[3]),
        "=&v"(nn[0]), "=&v"(nn[1]), "=&v"(nn[2]), "=&v"(nn[3])
      : "v"(q0), "v"(q1), "v"(q2), "v"(q3) : "memory");
}

// ---- coherent (sc0 sc1) WRITE-THROUGH store helpers ----
__device__ __forceinline__ void stg_f32(float* p, float v) {
  asm volatile("global_store_dword %0, %1, off sc0 sc1" :: "v"(p), "v"(v) : "memory");
}
__device__ __forceinline__ void stg_f32x2(float* p, f32x2 v) {
  asm volatile("global_store_dwordx2 %0, %1, off sc0 sc1" :: "v"(p), "v"(v) : "memory");
}
__device__ __forceinline__ void stg_u16(u16* p, u32 v) {
  asm volatile("global_store_short %0, %1, off sc0 sc1" :: "v"(p), "v"(v) : "memory");
}

// producer: drain write-through stores (vmcnt ack = at coherence point),
// barrier orders all waves' drains before tid0's counter bump.
__device__ __forceinline__ void flag_add(u32* ctrl, int fs) {
  vm_drain();
  __syncthreads();
  if (threadIdx.x == 0) atomicAdd(ctrl + fs, 1u);
}
// consumer: wave 0 polls ONE dword, everyone else parks at the barrier.
__device__ __forceinline__ void flag_wait_ge(u32* ctrl, int fs, u32 target, int warp) {
  if (warp == 0) {
    u32 v;
    do {
      v = __hip_atomic_load(ctrl + fs, __ATOMIC_RELAXED, __HIP_MEMORY_SCOPE_AGENT);
    } while (v < target);
  }
  __syncthreads();
}

// stage 16 rows x 512 f16 (coherent loads) -> LDS rows, stride 520 f16 (1040 B)
__device__ __forceinline__ void stage_rows(const u16* gsrc, char* lds, int tid) {
  const int row = tid >> 4, c = tid & 15;
  const u16* g = gsrc + row * 512 + c * 32;
  u32x4 a, b, cc, d;
  ldg4x16_off(g, a, b, cc, d);
  u32x4* dst = (u32x4*)(lds + row * 1040 + c * 64);
  dst[0] = a; dst[1] = b; dst[2] = cc; dst[3] = d;
}

#define MFMA(a, b, c) __builtin_amdgcn_mfma_f32_16x16x32_f16((a), (b), (c), 0, 0, 0)

extern "C" __global__ void __launch_bounds__(256, 1)
rnn_fused(const float* __restrict__ x, const float* __restrict__ attn_W,
          const float* __restrict__ attn_b, const float* __restrict__ comb_W,
          const float* __restrict__ comb_b, const float* __restrict__ w_ih,
          const float* __restrict__ w_hh, const float* __restrict__ b_ih,
          const float* __restrict__ b_hh, const float* __restrict__ out_W,
          const float* __restrict__ out_b, float* __restrict__ out,
          char* __restrict__ ws)
{
  const int tid  = threadIdx.x;
  const int lane = tid & 63;
  const int warp = tid >> 6;

  // ---- XCD role partition: (team, tb) from blockIdx, assuming XCD = bid%8 ----
  // XCD 0-3 slots 0-15: isA (tb 0-7), two teams per XCD.
  // XCD 4-7 slots 0-15: isW (tb 8-15), two teams per XCD.
  // all XCDs slots 16-31: C-only (tb 16-31, no weight traffic), team = XCD.
  int team, tb;
  {
    const int r = blockIdx.x & 7;    // presumed XCD
    const int s = blockIdx.x >> 3;   // slot on that XCD
    if (s < 16) {
      if (r < 4) { team = r * 2 + (s >> 3); tb = s & 7; }
      else       { team = (r - 4) * 2 + (s >> 3); tb = 8 + (s & 7); }
    } else {
      team = r; tb = s;
    }
  }

  const int tt   = tb * 256 + tid;      // team thread id
  const int gb0  = team * 16;
  const int lb   = tb >> 1;             // pair index -> batch
  const int half = tb & 1;              // m-half of x held by this block
  const int b    = gb0 + lb;            // this block's batch (x holder / stage C)
  const int m0h  = half * 256;

  u32* ctrl = (u32*)ws + team * 1024;   // 4 KB per team

  u16*   AW  = (u16*)(ws + OFF_AW);
  u16*   CW  = (u16*)(ws + OFF_CW);
  u16*   WIH = (u16*)(ws + OFF_WIH);
  u16*   WHH = (u16*)(ws + OFF_WHH);
  u16*   OW  = (u16*)(ws + OFF_OW);
  u16*   HB  = (u16*)(ws + OFF_HB);
  float* Sf  = (float*)(ws + OFF_SF);
  float* AP0 = (float*)(ws + OFF_AP0);
  float* AP1 = (float*)(ws + OFF_AP1);
  u16*   GB  = (u16*)(ws + OFF_GB);
  float* GH  = (float*)(ws + OFF_GH);
  u16*   XT  = (u16*)(ws + OFF_XT);

  __shared__ char smem[33408];
  float*     tbuf   = (float*)smem;           // [64][65] f32, init transpose only
  u32*       pLDS   = (u32*)smem;             // [128] packed f16 p-pairs (stage C)
  float*     redbuf = (float*)(smem + 512);   // [4][512] stage C partials
  float*     rbuf   = (float*)(smem + 8704);  // [8] softmax reduce scratch
  _Float16*  ldsF   = (_Float16*)smem;        // staged fragments, row stride 520
  _Float16*  xldsF  = (_Float16*)(smem + 16768); // x(:,t) [16][520] f16, live all step

  // ---- init handshake (per team): block tb==0 zeroes ctrl, sets magic ----
  if (tb == 0) {
    for (int i = 1 + tid; i < 1024; i += 256) ctrl[i] = 0u;
    __syncthreads();
    if (tid == 0) { __threadfence(); atomicExch(ctrl, MAGIC); }
  }
  if (tid == 0) {
    while (__hip_atomic_load(ctrl, __ATOMIC_RELAXED, __HIP_MEMORY_SCOPE_AGENT) != MAGIC) {}
    __threadfence();
  }
  __syncthreads();

  // ---- phase 0a: weights -> f16 (team-redundant, same-value benign races) ----
  for (int i = tt; i < 512 * 1024; i += 8192) AW[i]  = __builtin_bit_cast(u16, (_Float16)attn_W[i]);
  for (int i = tt; i < 512 * 1024; i += 8192) CW[i]  = __builtin_bit_cast(u16, (_Float16)comb_W[i]);
  for (int i = tt; i < 1536 * 512; i += 8192) WIH[i] = __builtin_bit_cast(u16, (_Float16)w_ih[i]);
  for (int i = tt; i < 1536 * 512; i += 8192) WHH[i] = __builtin_bit_cast(u16, (_Float16)w_hh[i]);
  for (int i = tt; i < 512 * 512;  i += 8192) OW[i]  = __builtin_bit_cast(u16, (_Float16)out_W[i]);
  HB[(size_t)gb0 * 512 + tt] = 0;   // h0 = 0

  // ---- phase 0b: transpose this block's m-half of x[b] into XT[b][t][m] (f16) ----
  {
    const float* xb  = x  + (size_t)b * 512 * 512;
    u16*         xtB = XT + (size_t)b * 512 * 512;
    for (int mt = 0; mt < 4; ++mt) {
      for (int ct = 0; ct < 8; ++ct) {
        for (int rr = warp; rr < 64; rr += 4)
          tbuf[rr * 65 + lane] = xb[(size_t)(m0h + mt * 64 + rr) * 512 + ct * 64 + lane];
        __syncthreads();
        for (int rr = warp; rr < 64; rr += 4)
          xtB[(size_t)(ct * 64 + rr) * 512 + m0h + mt * 64 + lane] =
              __builtin_bit_cast(u16, (_Float16)tbuf[lane * 65 + rr]);
        __syncthreads();
      }
    }
  }

  // init release (full fence: pushes weights/XT/HB to MALL), RDY counter, acquire
  vm_drain();
  __syncthreads();
  if (tid == 0) { __threadfence(); atomicAdd(ctrl + FS_RDY, 1u); }
  flag_wait_ge(ctrl, FS_RDY, 32u, warp);
  __threadfence();   // one-time acquire: L1/L2 inv so normal XT/weight loads are fresh

  // ---- phase 0c: register-resident x: rows t=lane*8+r, cols m0h+warp*64.. ----
  uint4 xr4[64];
  {
    const u16* base = XT + (size_t)b * 262144 + m0h + warp * 64;
#pragma unroll
    for (int r = 0; r < 8; ++r) {
      const uint4* row = (const uint4*)(base + (size_t)(lane * 8 + r) * 512);
#pragma unroll
      for (int jj = 0; jj < 8; ++jj) xr4[r * 8 + jj] = row[jj];
    }
  }

  const int  r16 = lane & 15, q = lane >> 4, q8 = q * 8;
  const bool isA = (tb < 8), isW = (tb >= 8 && tb < 16);
  const int  W4 = ((tb < 8) ? tb : tb - 8) * 4 + warp;
  const int  n0 = W4 * 16;

  float biasA = 0.f, biasD = 0.f, biasI0 = 0.f, biasI1 = 0.f, biasI2 = 0.f,
        biasH0 = 0.f, biasH1 = 0.f, biasH2 = 0.f, biasO = 0.f;
  if (isA) {
    biasA = attn_b[n0 + r16]; biasD = comb_b[n0 + r16];
    biasI0 = b_ih[n0 + r16]; biasI1 = b_ih[512 + n0 + r16]; biasI2 = b_ih[1024 + n0 + r16];
    biasO = out_b[n0 + r16];
  }
  if (isW) {
    biasH0 = b_hh[n0 + r16]; biasH1 = b_hh[512 + n0 + r16]; biasH2 = b_hh[1024 + n0 + r16];
  }

  // ---- x-prefetch registers (isA only): 64 B/thread of x(:,t), VALID values ----
  u32x4 xp0, xp1, xp2, xp3;
  const int xrow = tid >> 4, xc = tid & 15;   // batch row 0-15, 32-f16 chunk
  if (isA) {  // load x(:,0) now (waited); committed to LDS at top of step 0
    const u16* gp = XT + (size_t)(gb0 + xrow) * 262144 + xc * 32;
    ldg4x16_wait(gp, xp0, xp1, xp2, xp3);
  }

  float hreg[4] = {0.f, 0.f, 0.f, 0.f};

  for (int t = 0; t < 512; ++t) {
    const u32 tok = (u32)(t + 1);

    if (isA) {
      flag_wait_ge(ctrl, FS_H, 8u * (u32)t, warp);   // ends in barrier
      {  // commit x(:,t) to LDS (values valid since issue-time vmcnt(0))
        u32x4* dst = (u32x4*)((char*)xldsF + xrow * 1040 + xc * 64);
        dst[0] = xp0; dst[1] = xp1; dst[2] = xp2; dst[3] = xp3;
      }
      stage_rows(HB + gb0 * 512, smem, tid);         // coherent h -> LDS
      __syncthreads();
      // stage A: S = [x(:,t) | h] @ attn_W^T + attn_b   (x from LDS)
      f32x4 acc = {0.f, 0.f, 0.f, 0.f};
      const _Float16* aXl = xldsF + r16 * 520 + q8;
      const _Float16* aHl = ldsF + r16 * 520 + q8;
      const u16* bWp = AW + (size_t)(n0 + r16) * 1024 + q8;
#pragma unroll 4
      for (int k0 = 0; k0 < 512; k0 += 32)
        acc = MFMA(*(const f16x8*)(aXl + k0), *(const f16x8*)(bWp + k0), acc);
#pragma unroll 4
      for (int k0 = 0; k0 < 512; k0 += 32)
        acc = MFMA(*(const f16x8*)(aHl + k0), *(const f16x8*)(bWp + 512 + k0), acc);
#pragma unroll
      for (int i = 0; i < 4; ++i)
        stg_f32(Sf + (size_t)(gb0 + q * 4 + i) * 512 + n0 + r16, acc[i] + biasA);
      flag_add(ctrl, FS_S);
    } else if (isW) {
      flag_wait_ge(ctrl, FS_H, 8u * (u32)t, warp);
      stage_rows(HB + gb0 * 512, smem, tid);
      __syncthreads();
      // gh = h @ w_hh^T + b_hh (3 gate tiles, shared A-fragment)
      f32x4 a0 = {0.f,0.f,0.f,0.f}, a1 = {0.f,0.f,0.f,0.f}, a2 = {0.f,0.f,0.f,0.f};
      const _Float16* aHl = ldsF + r16 * 520 + q8;
      const u16* b0p = WHH + (size_t)(n0 + r16) * 512 + q8;
      const u16* b1p = WHH + (size_t)(512 + n0 + r16) * 512 + q8;
      const u16* b2p = WHH + (size_t)(1024 + n0 + r16) * 512 + q8;
#pragma unroll 4
      for (int k0 = 0; k0 < 512; k0 += 32) {
        f16x8 a = *(const f16x8*)(aHl + k0);
        a0 = MFMA(a, *(const f16x8*)(b0p + k0), a0);
        a1 = MFMA(a, *(const f16x8*)(b1p + k0), a1);
        a2 = MFMA(a, *(const f16x8*)(b2p + k0), a2);
      }
#pragma unroll
      for (int i = 0; i < 4; ++i) {
        const size_t ro = (size_t)(gb0 + q * 4 + i) * 1536;
        stg_f32(GH + ro + n0 + r16,        a0[i] + biasH0);
        stg_f32(GH + ro + 512 + n0 + r16,  a1[i] + biasH1);
        stg_f32(GH + ro + 1024 + n0 + r16, a2[i] + biasH2);
      }
      flag_add(ctrl, FS_GH);
    }

    // ---- all blocks: softmax (own batch) + applied partials from register x ----
    flag_wait_ge(ctrl, FS_S, 8u * tok, warp);
    {
      const int tc = 2 * tid;
      f32x2 sv;
      if (isA) {
        // fused: coherent Sf read + x(:,t+1) prefetch, one vmcnt(0).
        const int tp = (t < 511) ? t + 1 : t;   // clamp (t=511 load unused)
        const u16* gp = XT + (size_t)(gb0 + xrow) * 262144 + (size_t)tp * 512 + xc * 32;
        ldg_sf_x(Sf + (size_t)b * 512 + tc, gp, sv, xp0, xp1, xp2, xp3);
      } else {
        sv = ldg_f32x2(Sf + (size_t)b * 512 + tc);   // coherent read
      }
      float s0 = sv.x, s1 = sv.y;
      float mx = fmaxf(s0, s1);
#pragma unroll
      for (int off = 32; off; off >>= 1) mx = fmaxf(mx, __shfl_xor(mx, off, 64));
      if (lane == 0) rbuf[warp] = mx;
      __syncthreads();
      mx = fmaxf(fmaxf(rbuf[0], rbuf[1]), fmaxf(rbuf[2], rbuf[3]));
      float e0 = __expf(s0 - mx), e1 = __expf(s1 - mx);
      float sm = e0 + e1;
#pragma unroll
      for (int off = 32; off; off >>= 1) sm += __shfl_xor(sm, off, 64);
      if (lane == 0) rbuf[4 + warp] = sm;
      __syncthreads();
      sm = rbuf[4] + rbuf[5] + rbuf[6] + rbuf[7];
      const float inv = 1.f / sm;
      if ((tid >> 7) == half) {
        pLDS[tid & 127] = packh2(e0 * inv, e1 * inv);
      }
      __syncthreads();

      uint4 pz4[8];
      const uint4* pp = (const uint4*)pLDS + warp * 8;
#pragma unroll
      for (int jj = 0; jj < 8; ++jj) pz4[jj] = pp[jj];
      float accr[8];
#pragma unroll
      for (int r = 0; r < 8; ++r) {
        h2 sA = {(_Float16)0.f, (_Float16)0.f};
        h2 sB = {(_Float16)0.f, (_Float16)0.f};
#pragma unroll
        for (int jj = 0; jj < 8; ++jj) {
          uint4 xw = xr4[r * 8 + jj], pw = pz4[jj];
          sA = __builtin_bit_cast(h2, xw.x) * __builtin_bit_cast(h2, pw.x) + sA;
          sB = __builtin_bit_cast(h2, xw.y) * __builtin_bit_cast(h2, pw.y) + sB;
          sA = __builtin_bit_cast(h2, xw.z) * __builtin_bit_cast(h2, pw.z) + sA;
          sB = __builtin_bit_cast(h2, xw.w) * __builtin_bit_cast(h2, pw.w) + sB;
        }
        accr[r] = (float)sA.x + (float)sA.y + (float)sB.x + (float)sB.y;
      }
#pragma unroll
      for (int r = 0; r < 8; ++r) redbuf[warp * 512 + lane * 8 + r] = accr[r];
      __syncthreads();
      {
        float v0 = redbuf[tc]     + redbuf[512 + tc]     + redbuf[1024 + tc]     + redbuf[1536 + tc];
        float v1 = redbuf[tc + 1] + redbuf[512 + tc + 1] + redbuf[1024 + tc + 1] + redbuf[1536 + tc + 1];
        float* dst = (half ? AP1 : AP0) + (size_t)b * 512 + tc;
        f32x2 vv; vv.x = v0; vv.y = v1;
        stg_f32x2(dst, vv);
      }
      flag_add(ctrl, FS_C);
    }

    if (isA) {
      // stage D: g = relu([x(:,t) | applied] @ comb_W^T + comb_b); x-part first
      f32x4 acc = {0.f, 0.f, 0.f, 0.f};
      const _Float16* aXl = xldsF + r16 * 520 + q8;    // x from LDS (2nd reuse)
      const u16* bWp = CW + (size_t)(n0 + r16) * 1024 + q8;
#pragma unroll 4
      for (int k0 = 0; k0 < 512; k0 += 32)
        acc = MFMA(*(const f16x8*)(aXl + k0), *(const f16x8*)(bWp + k0), acc);
      flag_wait_ge(ctrl, FS_C, 32u * tok, warp);   // ends in barrier
      {  // stage applied = AP0+AP1 (16 coherent loads, ONE wait) -> f16 LDS rows
        const int row = tid >> 4, c = tid & 15;
        const float* g0 = AP0 + (size_t)(gb0 + row) * 512 + c * 32;
        const float* g1 = AP1 + (size_t)(gb0 + row) * 512 + c * 32;
        u32* dst = (u32*)(smem + row * 1040 + c * 64);
        u32x4 A[8], B[8];
        ldg_ap16(g0, g1, A, B);
#pragma unroll
        for (int k = 0; k < 8; ++k) {
          f32x4 s = __builtin_bit_cast(f32x4, A[k]) + __builtin_bit_cast(f32x4, B[k]);
          dst[2 * k]     = packh2(s[0], s[1]);
          dst[2 * k + 1] = packh2(s[2], s[3]);
        }
      }
      __syncthreads();
      const _Float16* aAl = ldsF + r16 * 520 + q8;
#pragma unroll 4
      for (int k0 = 0; k0 < 512; k0 += 32)
        acc = MFMA(*(const f16x8*)(aAl + k0), *(const f16x8*)(bWp + 512 + k0), acc);
#pragma unroll
      for (int i = 0; i < 4; ++i) {
        float g = fmaxf(acc[i] + biasD, 0.f);
        stg_u16(GB + (size_t)(gb0 + q * 4 + i) * 512 + n0 + r16,
                (u32)__builtin_bit_cast(u16, (_Float16)g));
      }
      flag_add(ctrl, FS_G);
      flag_wait_ge(ctrl, FS_G, 8u * tok, warp);
      stage_rows(GB + gb0 * 512, smem, tid);   // coherent g -> LDS
      __syncthreads();

      // stage EF: gi = g @ w_ih^T + b_ih (3 gates), then fused GRU pointwise
      f32x4 g0 = {0.f,0.f,0.f,0.f}, g1 = {0.f,0.f,0.f,0.f}, g2 = {0.f,0.f,0.f,0.f};
      const _Float16* aGl = ldsF + r16 * 520 + q8;
      const u16* w0p = WIH + (size_t)(n0 + r16) * 512 + q8;
      const u16* w1p = WIH + (size_t)(512 + n0 + r16) * 512 + q8;
      const u16* w2p = WIH + (size_t)(1024 + n0 + r16) * 512 + q8;
#pragma unroll 4
      for (int k0 = 0; k0 < 512; k0 += 32) {
        f16x8 a = *(const f16x8*)(aGl + k0);
        g0 = MFMA(a, *(const f16x8*)(w0p + k0), g0);
        g1 = MFMA(a, *(const f16x8*)(w1p + k0), g1);
        g2 = MFMA(a, *(const f16x8*)(w2p + k0), g2);
      }
      flag_wait_ge(ctrl, FS_GH, 8u * tok, warp);
      {
        const int j = n0 + r16;
        const float* q0p = GH + (size_t)(gb0 + q * 4 + 0) * 1536 + 512 + j;
        const float* q1p = GH + (size_t)(gb0 + q * 4 + 1) * 1536 + 512 + j;
        const float* q2p = GH + (size_t)(gb0 + q * 4 + 2) * 1536 + 512 + j;
        const float* q3p = GH + (size_t)(gb0 + q * 4 + 3) * 1536 + 512 + j;
        float ghr[4], ghz[4], ghn[4];
        ldg_gh12(q0p, q1p, q2p, q3p, ghr, ghz, ghn);   // 12 loads, ONE wait
#pragma unroll
        for (int i = 0; i < 4; ++i) {
          const int bi = gb0 + q * 4 + i;
          float gir = g0[i] + biasI0, giz = g1[i] + biasI1, gin = g2[i] + biasI2;
          float rg = sigmoidf_(gir + ghr[i]);
          float zg = sigmoidf_(giz + ghz[i]);
          float ng = tanhf_(gin + rg * ghn[i]);
          hreg[i] = (1.f - zg) * ng + zg * hreg[i];
          stg_u16(HB + (size_t)bi * 512 + j,
                  (u32)__builtin_bit_cast(u16, (_Float16)hreg[i]));
        }
      }
      flag_add(ctrl, FS_H);
    }
  }

  // ---- epilogue: out = h @ out_W^T + out_b ----
  if (isA) {
    flag_wait_ge(ctrl, FS_H, 8u * 512u, warp);
    stage_rows(HB + gb0 * 512, smem, tid);
    __syncthreads();
    f32x4 acc = {0.f, 0.f, 0.f, 0.f};
    const _Float16* aHl = ldsF + r16 * 520 + q8;
    const u16* bOp = OW + (size_t)(n0 + r16) * 512 + q8;
#pragma unroll 4
    for (int k0 = 0; k0 < 512; k0 += 32)
      acc = MFMA(*(const f16x8*)(aHl + k0), *(const f16x8*)(bOp + k0), acc);
#pragma unroll
    for (int i = 0; i < 4; ++i)
      out[(size_t)(gb0 + q * 4 + i) * 512 + n0 + r16] = acc[i] + biasO;
  }
}

extern "C" void kernel_launch(void* const* d_in, const int* in_sizes, int n_in,
                              void* d_out, int out_size, void* d_ws, size_t ws_size,
                              hipStream_t stream) {
  if (ws_size < (size_t)WS_NEED) return;
  rnn_fused<<<dim3(256), dim3(256), 0, stream>>>(
      (const float*)d_in[0], (const float*)d_in[1], (const float*)d_in[2],
      (const float*)d_in[3], (const float*)d_in[4], (const float*)d_in[5],
      (const float*)d_in[6], (const float*)d_in[7], (const float*)d_in[8],
      (const float*)d_in[9], (const float*)d_in[10],
      (float*)d_out, (char*)d_ws);
}

// Round 7
// 17198.239 us; speedup vs baseline: 1.3565x; 1.0297x over previous
//
#include <hip/hip_runtime.h>

// Persistent 8-team attention-GRU scan, register-resident x.
// Round-7: latency-shaving bundle on the per-step chain (H->S->C->G->H):
//  (1) isA: commit x(:,t)->LDS and run stage-A's x-half K-loop BEFORE the
//      FS_H wait (depends only on prefetch) -- fills the wait window.
//  (2) stage EF: FS_GH wait moved before staging; GB + 12 GH gate values
//      loaded in ONE asm block with ONE vmcnt(0) -- removes a serialized
//      MALL round trip from the EF segment.
//  (3) G exchange L2-localized: GB producers/consumers are the same team's
//      isA blocks, all on ONE XCD (round-4 mapping, HW-confirmed by the
//      FETCH collapse). GB stores are now plain write-back (L2 ack), reads
//      are sc0-only (L1-bypass, L2-hit). Both sides switched together.
// Round-6 x prefetch kept (fused waited-issue). Round-4 XCD role partition
// kept. Sync fabric unchanged (counter flags, wave-0 polls, write-through
// sc0sc1 stores for cross-XCD data).

typedef unsigned short u16;
typedef unsigned int u32;
typedef _Float16 h2 __attribute__((ext_vector_type(2)));
typedef _Float16 f16x8 __attribute__((ext_vector_type(8)));
typedef float f32x4 __attribute__((ext_vector_type(4)));
typedef float f32x2 __attribute__((ext_vector_type(2)));
typedef u32 u32x4 __attribute__((ext_vector_type(4)));

#define MAGIC 0x13579BDFu

// ---- workspace layout (bytes) ----
#define OFF_AW   65536      // attn_W f16 [512][1024]
#define OFF_CW   1114112    // comb_W f16 [512][1024]
#define OFF_WIH  2162688    // w_ih  f16 [1536][512]
#define OFF_WHH  3735552    // w_hh  f16 [1536][512]
#define OFF_OW   5308416    // out_W f16 [512][512]
#define OFF_HB   5832704    // h f16 [128][512]
#define OFF_SF   5963776    // scores f32 [128][512]
#define OFF_AP0  6225920    // applied half0 partial f32 [128][512]
#define OFF_AP1  6488064    // applied half1 partial f32 [128][512]
#define OFF_GB   6750208    // g f16 [128][512]
#define OFF_GH   6881280    // gh f32 [128][1536] (flat)
#define OFF_XT   7667712    // x^T f16 [128 b][512 t][512 m]  64 MiB
#define WS_NEED  74776576

// per-stage counter slots (u32 index into per-team ctrl[1024]); 128B apart
#define FS_S   64
#define FS_C   96
#define FS_G   128
#define FS_GH  160
#define FS_H   192
#define FS_RDY 224

__device__ __forceinline__ float sigmoidf_(float v) { return 1.f / (1.f + __expf(-v)); }
__device__ __forceinline__ float tanhf_(float v) {
  v = fminf(fmaxf(v, -15.f), 15.f);
  float e2 = __expf(2.f * v);
  return (e2 - 1.f) / (e2 + 1.f);
}
__device__ __forceinline__ u32 packh2(float a, float b) {
  h2 v; v.x = (_Float16)a; v.y = (_Float16)b;
  return __builtin_bit_cast(u32, v);
}

__device__ __forceinline__ void vm_drain() { asm volatile("s_waitcnt vmcnt(0)" ::: "memory"); }

// ---- coherent (sc0 sc1) LOAD helpers ----
__device__ __forceinline__ f32x2 ldg_f32x2(const void* p) {
  f32x2 r;
  asm volatile("global_load_dwordx2 %0, %1, off sc0 sc1\n\ts_waitcnt vmcnt(0)"
               : "=v"(r) : "v"(p) : "memory");
  return r;
}
// 4 x dwordx4 from one base via offset immediates, one wait (coherent/MALL)
__device__ __forceinline__ void ldg4x16_off(const void* p, u32x4& a, u32x4& b, u32x4& c, u32x4& d) {
  asm volatile(
      "global_load_dwordx4 %0, %4, off sc0 sc1\n\t"
      "global_load_dwordx4 %1, %4, off offset:16 sc0 sc1\n\t"
      "global_load_dwordx4 %2, %4, off offset:32 sc0 sc1\n\t"
      "global_load_dwordx4 %3, %4, off offset:48 sc0 sc1\n\t"
      "s_waitcnt vmcnt(0)"
      : "=&v"(a), "=&v"(b), "=&v"(c), "=&v"(d)
      : "v"(p) : "memory");
}
// 4 x dwordx4 NORMAL-cached loads, WAITED (values valid at exit).
__device__ __forceinline__ void ldg4x16_wait(const void* p, u32x4& a, u32x4& b, u32x4& c, u32x4& d) {
  asm volatile(
      "global_load_dwordx4 %0, %4, off\n\t"
      "global_load_dwordx4 %1, %4, off offset:16\n\t"
      "global_load_dwordx4 %2, %4, off offset:32\n\t"
      "global_load_dwordx4 %3, %4, off offset:48\n\t"
      "s_waitcnt vmcnt(0)"
      : "=&v"(a), "=&v"(b), "=&v"(c), "=&v"(d)
      : "v"(p) : "memory");
}
// fused: coherent Sf dwordx2 + 4 normal x-prefetch dwordx4, ONE wait.
__device__ __forceinline__ void ldg_sf_x(const float* sp, const u16* xp, f32x2& sv,
                                         u32x4& a, u32x4& b, u32x4& c, u32x4& d) {
  asm volatile(
      "global_load_dwordx2 %0, %5, off sc0 sc1\n\t"
      "global_load_dwordx4 %1, %6, off\n\t"
      "global_load_dwordx4 %2, %6, off offset:16\n\t"
      "global_load_dwordx4 %3, %6, off offset:32\n\t"
      "global_load_dwordx4 %4, %6, off offset:48\n\t"
      "s_waitcnt vmcnt(0)"
      : "=&v"(sv), "=&v"(a), "=&v"(b), "=&v"(c), "=&v"(d)
      : "v"(sp), "v"(xp) : "memory");
}
// 16 x dwordx4 (two 128B-contiguous rows), ONE wait.
__device__ __forceinline__ void ldg_ap16(const float* pa, const float* pb,
                                         u32x4 (&A)[8], u32x4 (&B)[8]) {
  asm volatile(
      "global_load_dwordx4 %0, %16, off sc0 sc1\n\t"
      "global_load_dwordx4 %1, %16, off offset:16 sc0 sc1\n\t"
      "global_load_dwordx4 %2, %16, off offset:32 sc0 sc1\n\t"
      "global_load_dwordx4 %3, %16, off offset:48 sc0 sc1\n\t"
      "global_load_dwordx4 %4, %16, off offset:64 sc0 sc1\n\t"
      "global_load_dwordx4 %5, %16, off offset:80 sc0 sc1\n\t"
      "global_load_dwordx4 %6, %16, off offset:96 sc0 sc1\n\t"
      "global_load_dwordx4 %7, %16, off offset:112 sc0 sc1\n\t"
      "global_load_dwordx4 %8, %17, off sc0 sc1\n\t"
      "global_load_dwordx4 %9, %17, off offset:16 sc0 sc1\n\t"
      "global_load_dwordx4 %10, %17, off offset:32 sc0 sc1\n\t"
      "global_load_dwordx4 %11, %17, off offset:48 sc0 sc1\n\t"
      "global_load_dwordx4 %12, %17, off offset:64 sc0 sc1\n\t"
      "global_load_dwordx4 %13, %17, off offset:80 sc0 sc1\n\t"
      "global_load_dwordx4 %14, %17, off offset:96 sc0 sc1\n\t"
      "global_load_dwordx4 %15, %17, off offset:112 sc0 sc1\n\t"
      "s_waitcnt vmcnt(0)"
      : "=&v"(A[0]), "=&v"(A[1]), "=&v"(A[2]), "=&v"(A[3]),
        "=&v"(A[4]), "=&v"(A[5]), "=&v"(A[6]), "=&v"(A[7]),
        "=&v"(B[0]), "=&v"(B[1]), "=&v"(B[2]), "=&v"(B[3]),
        "=&v"(B[4]), "=&v"(B[5]), "=&v"(B[6]), "=&v"(B[7])
      : "v"(pa), "v"(pb) : "memory");
}
// fused stage-EF staging: 4 x dwordx4 GB (sc0-only: same-XCD L2 exchange)
// + 12 GH gate dwords (sc0sc1: cross-XCD via MALL), ONE wait.
__device__ __forceinline__ void ldg_gb_gh(const u16* g, const float* q0, const float* q1,
                                          const float* q2, const float* q3,
                                          u32x4& a, u32x4& b, u32x4& c, u32x4& d,
                                          float (&rr)[4], float (&zz)[4], float (&nn)[4]) {
  asm volatile(
      "global_load_dwordx4 %0, %16, off sc0\n\t"
      "global_load_dwordx4 %1, %16, off offset:16 sc0\n\t"
      "global_load_dwordx4 %2, %16, off offset:32 sc0\n\t"
      "global_load_dwordx4 %3, %16, off offset:48 sc0\n\t"
      "global_load_dword %4, %17, off offset:-2048 sc0 sc1\n\t"
      "global_load_dword %8, %17, off sc0 sc1\n\t"
      "global_load_dword %12, %17, off offset:2048 sc0 sc1\n\t"
      "global_load_dword %5, %18, off offset:-2048 sc0 sc1\n\t"
      "global_load_dword %9, %18, off sc0 sc1\n\t"
      "global_load_dword %13, %18, off offset:2048 sc0 sc1\n\t"
      "global_load_dword %6, %19, off offset:-2048 sc0 sc1\n\t"
      "global_load_dword %10, %19, off sc0 sc1\n\t"
      "global_load_dword %14, %19, off offset:2048 sc0 sc1\n\t"
      "global_load_dword %7, %20, off offset:-2048 sc0 sc1\n\t"
      "global_load_dword %11, %20, off sc0 sc1\n\t"
      "global_load_dword %15, %20, off offset:2048 sc0 sc1\n\t"
      "s_waitcnt vmcnt(0)"
      : "=&v"(a), "=&v"(b), "=&v"(c), "=&v"(d),
        "=&v"(rr[0]), "=&v"(rr[1]), "=&v"(rr[2]), "=&v"(rr[3]),
        "=&v"(zz[0]), "=&v"(zz[1]), "=&v"(zz[2]), "=&v"(zz[3]),
        "=&v"(nn[0]), "=&v"(nn[1]), "=&v"(nn[2]), "=&v"(nn[3])
      : "v"(g), "v"(q0), "v"(q1), "v"(q2), "v"(q3) : "memory");
}

// ---- coherent (sc0 sc1) WRITE-THROUGH store helpers ----
__device__ __forceinline__ void stg_f32(float* p, float v) {
  asm volatile("global_store_dword %0, %1, off sc0 sc1" :: "v"(p), "v"(v) : "memory");
}
__device__ __forceinline__ void stg_f32x2(float* p, f32x2 v) {
  asm volatile("global_store_dwordx2 %0, %1, off sc0 sc1" :: "v"(p), "v"(v) : "memory");
}
__device__ __forceinline__ void stg_u16(u16* p, u32 v) {
  asm volatile("global_store_short %0, %1, off sc0 sc1" :: "v"(p), "v"(v) : "memory");
}

// producer: drain stores (write-through: MALL ack; normal: L2 ack),
// barrier orders all waves' drains before tid0's counter bump.
__device__ __forceinline__ void flag_add(u32* ctrl, int fs) {
  vm_drain();
  __syncthreads();
  if (threadIdx.x == 0) atomicAdd(ctrl + fs, 1u);
}
// consumer: wave 0 polls ONE dword, everyone else parks at the barrier.
__device__ __forceinline__ void flag_wait_ge(u32* ctrl, int fs, u32 target, int warp) {
  if (warp == 0) {
    u32 v;
    do {
      v = __hip_atomic_load(ctrl + fs, __ATOMIC_RELAXED, __HIP_MEMORY_SCOPE_AGENT);
    } while (v < target);
  }
  __syncthreads();
}

// stage 16 rows x 512 f16 (coherent loads) -> LDS rows, stride 520 f16 (1040 B)
__device__ __forceinline__ void stage_rows(const u16* gsrc, char* lds, int tid) {
  const int row = tid >> 4, c = tid & 15;
  const u16* g = gsrc + row * 512 + c * 32;
  u32x4 a, b, cc, d;
  ldg4x16_off(g, a, b, cc, d);
  u32x4* dst = (u32x4*)(lds + row * 1040 + c * 64);
  dst[0] = a; dst[1] = b; dst[2] = cc; dst[3] = d;
}

#define MFMA(a, b, c) __builtin_amdgcn_mfma_f32_16x16x32_f16((a), (b), (c), 0, 0, 0)

extern "C" __global__ void __launch_bounds__(256, 1)
rnn_fused(const float* __restrict__ x, const float* __restrict__ attn_W,
          const float* __restrict__ attn_b, const float* __restrict__ comb_W,
          const float* __restrict__ comb_b, const float* __restrict__ w_ih,
          const float* __restrict__ w_hh, const float* __restrict__ b_ih,
          const float* __restrict__ b_hh, const float* __restrict__ out_W,
          const float* __restrict__ out_b, float* __restrict__ out,
          char* __restrict__ ws)
{
  const int tid  = threadIdx.x;
  const int lane = tid & 63;
  const int warp = tid >> 6;

  // ---- XCD role partition: (team, tb) from blockIdx, XCD = bid%8 (confirmed) ----
  int team, tb;
  {
    const int r = blockIdx.x & 7;    // XCD
    const int s = blockIdx.x >> 3;   // slot on that XCD
    if (s < 16) {
      if (r < 4) { team = r * 2 + (s >> 3); tb = s & 7; }
      else       { team = (r - 4) * 2 + (s >> 3); tb = 8 + (s & 7); }
    } else {
      team = r; tb = s;
    }
  }

  const int tt   = tb * 256 + tid;      // team thread id
  const int gb0  = team * 16;
  const int lb   = tb >> 1;             // pair index -> batch
  const int half = tb & 1;              // m-half of x held by this block
  const int b    = gb0 + lb;            // this block's batch (x holder / stage C)
  const int m0h  = half * 256;

  u32* ctrl = (u32*)ws + team * 1024;   // 4 KB per team

  u16*   AW  = (u16*)(ws + OFF_AW);
  u16*   CW  = (u16*)(ws + OFF_CW);
  u16*   WIH = (u16*)(ws + OFF_WIH);
  u16*   WHH = (u16*)(ws + OFF_WHH);
  u16*   OW  = (u16*)(ws + OFF_OW);
  u16*   HB  = (u16*)(ws + OFF_HB);
  float* Sf  = (float*)(ws + OFF_SF);
  float* AP0 = (float*)(ws + OFF_AP0);
  float* AP1 = (float*)(ws + OFF_AP1);
  u16*   GB  = (u16*)(ws + OFF_GB);
  float* GH  = (float*)(ws + OFF_GH);
  u16*   XT  = (u16*)(ws + OFF_XT);

  __shared__ char smem[33408];
  float*     tbuf   = (float*)smem;           // [64][65] f32, init transpose only
  u32*       pLDS   = (u32*)smem;             // [128] packed f16 p-pairs (stage C)
  float*     redbuf = (float*)(smem + 512);   // [4][512] stage C partials
  float*     rbuf   = (float*)(smem + 8704);  // [8] softmax reduce scratch
  _Float16*  ldsF   = (_Float16*)smem;        // staged fragments, row stride 520
  _Float16*  xldsF  = (_Float16*)(smem + 16768); // x(:,t) [16][520] f16, live all step

  // ---- init handshake (per team): block tb==0 zeroes ctrl, sets magic ----
  if (tb == 0) {
    for (int i = 1 + tid; i < 1024; i += 256) ctrl[i] = 0u;
    __syncthreads();
    if (tid == 0) { __threadfence(); atomicExch(ctrl, MAGIC); }
  }
  if (tid == 0) {
    while (__hip_atomic_load(ctrl, __ATOMIC_RELAXED, __HIP_MEMORY_SCOPE_AGENT) != MAGIC) {}
    __threadfence();
  }
  __syncthreads();

  // ---- phase 0a: weights -> f16 (team-redundant, same-value benign races) ----
  for (int i = tt; i < 512 * 1024; i += 8192) AW[i]  = __builtin_bit_cast(u16, (_Float16)attn_W[i]);
  for (int i = tt; i < 512 * 1024; i += 8192) CW[i]  = __builtin_bit_cast(u16, (_Float16)comb_W[i]);
  for (int i = tt; i < 1536 * 512; i += 8192) WIH[i] = __builtin_bit_cast(u16, (_Float16)w_ih[i]);
  for (int i = tt; i < 1536 * 512; i += 8192) WHH[i] = __builtin_bit_cast(u16, (_Float16)w_hh[i]);
  for (int i = tt; i < 512 * 512;  i += 8192) OW[i]  = __builtin_bit_cast(u16, (_Float16)out_W[i]);
  HB[(size_t)gb0 * 512 + tt] = 0;   // h0 = 0

  // ---- phase 0b: transpose this block's m-half of x[b] into XT[b][t][m] (f16) ----
  {
    const float* xb  = x  + (size_t)b * 512 * 512;
    u16*         xtB = XT + (size_t)b * 512 * 512;
    for (int mt = 0; mt < 4; ++mt) {
      for (int ct = 0; ct < 8; ++ct) {
        for (int rr = warp; rr < 64; rr += 4)
          tbuf[rr * 65 + lane] = xb[(size_t)(m0h + mt * 64 + rr) * 512 + ct * 64 + lane];
        __syncthreads();
        for (int rr = warp; rr < 64; rr += 4)
          xtB[(size_t)(ct * 64 + rr) * 512 + m0h + mt * 64 + lane] =
              __builtin_bit_cast(u16, (_Float16)tbuf[lane * 65 + rr]);
        __syncthreads();
      }
    }
  }

  // init release (full fence: pushes weights/XT/HB to MALL), RDY counter, acquire
  vm_drain();
  __syncthreads();
  if (tid == 0) { __threadfence(); atomicAdd(ctrl + FS_RDY, 1u); }
  flag_wait_ge(ctrl, FS_RDY, 32u, warp);
  __threadfence();   // one-time acquire: L1/L2 inv so normal XT/weight loads are fresh

  // ---- phase 0c: register-resident x: rows t=lane*8+r, cols m0h+warp*64.. ----
  uint4 xr4[64];
  {
    const u16* base = XT + (size_t)b * 262144 + m0h + warp * 64;
#pragma unroll
    for (int r = 0; r < 8; ++r) {
      const uint4* row = (const uint4*)(base + (size_t)(lane * 8 + r) * 512);
#pragma unroll
      for (int jj = 0; jj < 8; ++jj) xr4[r * 8 + jj] = row[jj];
    }
  }

  const int  r16 = lane & 15, q = lane >> 4, q8 = q * 8;
  const bool isA = (tb < 8), isW = (tb >= 8 && tb < 16);
  const int  W4 = ((tb < 8) ? tb : tb - 8) * 4 + warp;
  const int  n0 = W4 * 16;

  float biasA = 0.f, biasD = 0.f, biasI0 = 0.f, biasI1 = 0.f, biasI2 = 0.f,
        biasH0 = 0.f, biasH1 = 0.f, biasH2 = 0.f, biasO = 0.f;
  if (isA) {
    biasA = attn_b[n0 + r16]; biasD = comb_b[n0 + r16];
    biasI0 = b_ih[n0 + r16]; biasI1 = b_ih[512 + n0 + r16]; biasI2 = b_ih[1024 + n0 + r16];
    biasO = out_b[n0 + r16];
  }
  if (isW) {
    biasH0 = b_hh[n0 + r16]; biasH1 = b_hh[512 + n0 + r16]; biasH2 = b_hh[1024 + n0 + r16];
  }

  // ---- x-prefetch registers (isA only): 64 B/thread of x(:,t), VALID values ----
  u32x4 xp0, xp1, xp2, xp3;
  const int xrow = tid >> 4, xc = tid & 15;   // batch row 0-15, 32-f16 chunk
  if (isA) {  // load x(:,0) now (waited); committed to LDS at top of step 0
    const u16* gp = XT + (size_t)(gb0 + xrow) * 262144 + xc * 32;
    ldg4x16_wait(gp, xp0, xp1, xp2, xp3);
  }

  float hreg[4] = {0.f, 0.f, 0.f, 0.f};

  for (int t = 0; t < 512; ++t) {
    const u32 tok = (u32)(t + 1);

    if (isA) {
      // ---- pre-H work: commit x(:,t) to LDS, run stage-A's x-half K-loop ----
      {
        u32x4* dst = (u32x4*)((char*)xldsF + xrow * 1040 + xc * 64);
        dst[0] = xp0; dst[1] = xp1; dst[2] = xp2; dst[3] = xp3;
      }
      __syncthreads();                       // xlds visible to all waves
      f32x4 acc = {0.f, 0.f, 0.f, 0.f};
      const _Float16* aXl = xldsF + r16 * 520 + q8;
      const u16* bWp = AW + (size_t)(n0 + r16) * 1024 + q8;
#pragma unroll 4
      for (int k0 = 0; k0 < 512; k0 += 32)
        acc = MFMA(*(const f16x8*)(aXl + k0), *(const f16x8*)(bWp + k0), acc);
      // ---- now wait for h(t-1), stage it, and finish stage A ----
      flag_wait_ge(ctrl, FS_H, 8u * (u32)t, warp);   // ends in barrier
      stage_rows(HB + gb0 * 512, smem, tid);         // coherent h -> LDS
      __syncthreads();
      const _Float16* aHl = ldsF + r16 * 520 + q8;
#pragma unroll 4
      for (int k0 = 0; k0 < 512; k0 += 32)
        acc = MFMA(*(const f16x8*)(aHl + k0), *(const f16x8*)(bWp + 512 + k0), acc);
#pragma unroll
      for (int i = 0; i < 4; ++i)
        stg_f32(Sf + (size_t)(gb0 + q * 4 + i) * 512 + n0 + r16, acc[i] + biasA);
      flag_add(ctrl, FS_S);
    } else if (isW) {
      flag_wait_ge(ctrl, FS_H, 8u * (u32)t, warp);
      stage_rows(HB + gb0 * 512, smem, tid);
      __syncthreads();
      // gh = h @ w_hh^T + b_hh (3 gate tiles, shared A-fragment)
      f32x4 a0 = {0.f,0.f,0.f,0.f}, a1 = {0.f,0.f,0.f,0.f}, a2 = {0.f,0.f,0.f,0.f};
      const _Float16* aHl = ldsF + r16 * 520 + q8;
      const u16* b0p = WHH + (size_t)(n0 + r16) * 512 + q8;
      const u16* b1p = WHH + (size_t)(512 + n0 + r16) * 512 + q8;
      const u16* b2p = WHH + (size_t)(1024 + n0 + r16) * 512 + q8;
#pragma unroll 4
      for (int k0 = 0; k0 < 512; k0 += 32) {
        f16x8 a = *(const f16x8*)(aHl + k0);
        a0 = MFMA(a, *(const f16x8*)(b0p + k0), a0);
        a1 = MFMA(a, *(const f16x8*)(b1p + k0), a1);
        a2 = MFMA(a, *(const f16x8*)(b2p + k0), a2);
      }
#pragma unroll
      for (int i = 0; i < 4; ++i) {
        const size_t ro = (size_t)(gb0 + q * 4 + i) * 1536;
        stg_f32(GH + ro + n0 + r16,        a0[i] + biasH0);
        stg_f32(GH + ro + 512 + n0 + r16,  a1[i] + biasH1);
        stg_f32(GH + ro + 1024 + n0 + r16, a2[i] + biasH2);
      }
      flag_add(ctrl, FS_GH);
    }

    // ---- all blocks: softmax (own batch) + applied partials from register x ----
    flag_wait_ge(ctrl, FS_S, 8u * tok, warp);
    {
      const int tc = 2 * tid;
      f32x2 sv;
      if (isA) {
        // fused: coherent Sf read + x(:,t+1) prefetch, one vmcnt(0).
        const int tp = (t < 511) ? t + 1 : t;   // clamp (t=511 load unused)
        const u16* gp = XT + (size_t)(gb0 + xrow) * 262144 + (size_t)tp * 512 + xc * 32;
        ldg_sf_x(Sf + (size_t)b * 512 + tc, gp, sv, xp0, xp1, xp2, xp3);
      } else {
        sv = ldg_f32x2(Sf + (size_t)b * 512 + tc);   // coherent read
      }
      float s0 = sv.x, s1 = sv.y;
      float mx = fmaxf(s0, s1);
#pragma unroll
      for (int off = 32; off; off >>= 1) mx = fmaxf(mx, __shfl_xor(mx, off, 64));
      if (lane == 0) rbuf[warp] = mx;
      __syncthreads();
      mx = fmaxf(fmaxf(rbuf[0], rbuf[1]), fmaxf(rbuf[2], rbuf[3]));
      float e0 = __expf(s0 - mx), e1 = __expf(s1 - mx);
      float sm = e0 + e1;
#pragma unroll
      for (int off = 32; off; off >>= 1) sm += __shfl_xor(sm, off, 64);
      if (lane == 0) rbuf[4 + warp] = sm;
      __syncthreads();
      sm = rbuf[4] + rbuf[5] + rbuf[6] + rbuf[7];
      const float inv = 1.f / sm;
      if ((tid >> 7) == half) {
        pLDS[tid & 127] = packh2(e0 * inv, e1 * inv);
      }
      __syncthreads();

      uint4 pz4[8];
      const uint4* pp = (const uint4*)pLDS + warp * 8;
#pragma unroll
      for (int jj = 0; jj < 8; ++jj) pz4[jj] = pp[jj];
      float accr[8];
#pragma unroll
      for (int r = 0; r < 8; ++r) {
        h2 sA = {(_Float16)0.f, (_Float16)0.f};
        h2 sB = {(_Float16)0.f, (_Float16)0.f};
#pragma unroll
        for (int jj = 0; jj < 8; ++jj) {
          uint4 xw = xr4[r * 8 + jj], pw = pz4[jj];
          sA = __builtin_bit_cast(h2, xw.x) * __builtin_bit_cast(h2, pw.x) + sA;
          sB = __builtin_bit_cast(h2, xw.y) * __builtin_bit_cast(h2, pw.y) + sB;
          sA = __builtin_bit_cast(h2, xw.z) * __builtin_bit_cast(h2, pw.z) + sA;
          sB = __builtin_bit_cast(h2, xw.w) * __builtin_bit_cast(h2, pw.w) + sB;
        }
        accr[r] = (float)sA.x + (float)sA.y + (float)sB.x + (float)sB.y;
      }
#pragma unroll
      for (int r = 0; r < 8; ++r) redbuf[warp * 512 + lane * 8 + r] = accr[r];
      __syncthreads();
      {
        float v0 = redbuf[tc]     + redbuf[512 + tc]     + redbuf[1024 + tc]     + redbuf[1536 + tc];
        float v1 = redbuf[tc + 1] + redbuf[512 + tc + 1] + redbuf[1024 + tc + 1] + redbuf[1536 + tc + 1];
        float* dst = (half ? AP1 : AP0) + (size_t)b * 512 + tc;
        f32x2 vv; vv.x = v0; vv.y = v1;
        stg_f32x2(dst, vv);
      }
      flag_add(ctrl, FS_C);
    }

    if (isA) {
      // stage D: g = relu([x(:,t) | applied] @ comb_W^T + comb_b); x-part first
      f32x4 acc = {0.f, 0.f, 0.f, 0.f};
      const _Float16* aXl = xldsF + r16 * 520 + q8;    // x from LDS (2nd reuse)
      const u16* bWp = CW + (size_t)(n0 + r16) * 1024 + q8;
#pragma unroll 4
      for (int k0 = 0; k0 < 512; k0 += 32)
        acc = MFMA(*(const f16x8*)(aXl + k0), *(const f16x8*)(bWp + k0), acc);
      flag_wait_ge(ctrl, FS_C, 32u * tok, warp);   // ends in barrier
      {  // stage applied = AP0+AP1 (16 coherent loads, ONE wait) -> f16 LDS rows
        const int row = tid >> 4, c = tid & 15;
        const float* g0 = AP0 + (size_t)(gb0 + row) * 512 + c * 32;
        const float* g1 = AP1 + (size_t)(gb0 + row) * 512 + c * 32;
        u32* dst = (u32*)(smem + row * 1040 + c * 64);
        u32x4 A[8], B[8];
        ldg_ap16(g0, g1, A, B);
#pragma unroll
        for (int k = 0; k < 8; ++k) {
          f32x4 s = __builtin_bit_cast(f32x4, A[k]) + __builtin_bit_cast(f32x4, B[k]);
          dst[2 * k]     = packh2(s[0], s[1]);
          dst[2 * k + 1] = packh2(s[2], s[3]);
        }
      }
      __syncthreads();
      const _Float16* aAl = ldsF + r16 * 520 + q8;
#pragma unroll 4
      for (int k0 = 0; k0 < 512; k0 += 32)
        acc = MFMA(*(const f16x8*)(aAl + k0), *(const f16x8*)(bWp + 512 + k0), acc);
#pragma unroll
      for (int i = 0; i < 4; ++i) {
        float g = fmaxf(acc[i] + biasD, 0.f);
        // NORMAL store: G exchange is same-XCD (all isA of a team), L2-coherent.
        GB[(size_t)(gb0 + q * 4 + i) * 512 + n0 + r16] =
            __builtin_bit_cast(u16, (_Float16)g);
      }
      flag_add(ctrl, FS_G);                       // drain = L2 ack (fast)
      flag_wait_ge(ctrl, FS_G, 8u * tok, warp);
      flag_wait_ge(ctrl, FS_GH, 8u * tok, warp);  // GH ready long ago
      float ghr[4], ghz[4], ghn[4];
      {  // fused: GB (sc0, L2) + 12 GH gates (sc0sc1, MALL), ONE wait
        const int row = tid >> 4, c = tid & 15;
        const u16* g = GB + (size_t)(gb0 + row) * 512 + c * 32;
        const int j = n0 + r16;
        const float* q0p = GH + (size_t)(gb0 + q * 4 + 0) * 1536 + 512 + j;
        const float* q1p = GH + (size_t)(gb0 + q * 4 + 1) * 1536 + 512 + j;
        const float* q2p = GH + (size_t)(gb0 + q * 4 + 2) * 1536 + 512 + j;
        const float* q3p = GH + (size_t)(gb0 + q * 4 + 3) * 1536 + 512 + j;
        u32x4 A, B, C, D;
        ldg_gb_gh(g, q0p, q1p, q2p, q3p, A, B, C, D, ghr, ghz, ghn);
        u32x4* dst = (u32x4*)(smem + row * 1040 + c * 64);
        dst[0] = A; dst[1] = B; dst[2] = C; dst[3] = D;
      }
      __syncthreads();

      // stage EF: gi = g @ w_ih^T + b_ih (3 gates), then fused GRU pointwise
      f32x4 g0 = {0.f,0.f,0.f,0.f}, g1 = {0.f,0.f,0.f,0.f}, g2 = {0.f,0.f,0.f,0.f};
      const _Float16* aGl = ldsF + r16 * 520 + q8;
      const u16* w0p = WIH + (size_t)(n0 + r16) * 512 + q8;
      const u16* w1p = WIH + (size_t)(512 + n0 + r16) * 512 + q8;
      const u16* w2p = WIH + (size_t)(1024 + n0 + r16) * 512 + q8;
#pragma unroll 4
      for (int k0 = 0; k0 < 512; k0 += 32) {
        f16x8 a = *(const f16x8*)(aGl + k0);
        g0 = MFMA(a, *(const f16x8*)(w0p + k0), g0);
        g1 = MFMA(a, *(const f16x8*)(w1p + k0), g1);
        g2 = MFMA(a, *(const f16x8*)(w2p + k0), g2);
      }
#pragma unroll
      for (int i = 0; i < 4; ++i) {
        const int bi = gb0 + q * 4 + i;
        const int j = n0 + r16;
        float gir = g0[i] + biasI0, giz = g1[i] + biasI1, gin = g2[i] + biasI2;
        float rg = sigmoidf_(gir + ghr[i]);
        float zg = sigmoidf_(giz + ghz[i]);
        float ng = tanhf_(gin + rg * ghn[i]);
        hreg[i] = (1.f - zg) * ng + zg * hreg[i];
        stg_u16(HB + (size_t)bi * 512 + j,
                (u32)__builtin_bit_cast(u16, (_Float16)hreg[i]));
      }
      flag_add(ctrl, FS_H);
    }
  }

  // ---- epilogue: out = h @ out_W^T + out_b ----
  if (isA) {
    flag_wait_ge(ctrl, FS_H, 8u * 512u, warp);
    stage_rows(HB + gb0 * 512, smem, tid);
    __syncthreads();
    f32x4 acc = {0.f, 0.f, 0.f, 0.f};
    const _Float16* aHl = ldsF + r16 * 520 + q8;
    const u16* bOp = OW + (size_t)(n0 + r16) * 512 + q8;
#pragma unroll 4
    for (int k0 = 0; k0 < 512; k0 += 32)
      acc = MFMA(*(const f16x8*)(aHl + k0), *(const f16x8*)(bOp + k0), acc);
#pragma unroll
    for (int i = 0; i < 4; ++i)
      out[(size_t)(gb0 + q * 4 + i) * 512 + n0 + r16] = acc[i] + biasO;
  }
}

extern "C" void kernel_launch(void* const* d_in, const int* in_sizes, int n_in,
                              void* d_out, int out_size, void* d_ws, size_t ws_size,
                              hipStream_t stream) {
  if (ws_size < (size_t)WS_NEED) return;
  rnn_fused<<<dim3(256), dim3(256), 0, stream>>>(
      (const float*)d_in[0], (const float*)d_in[1], (const float*)d_in[2],
      (const float*)d_in[3], (const float*)d_in[4], (const float*)d_in[5],
      (const float*)d_in[6], (const float*)d_in[7], (const float*)d_in[8],
      (const float*)d_in[9], (const float*)d_in[10],
      (float*)d_out, (char*)d_ws);
}